// Round 3
// baseline (295.238 us; speedup 1.0000x reference)
//
#include <hip/hip_runtime.h>
#include <hip/hip_bf16.h>

// Problem constants
#define Nn   32
#define Ee   512
#define DIN  300
#define DOUT 300
#define NT   4
#define QD   300
#define SLOPE 0.2f
#define ROWS 32   // rows per block in attn kernel
#define CPAD 320  // padded d-dim for hmT (20 MFMA n-tiles of 16)

typedef __attribute__((ext_vector_type(8))) short bf16x8;
typedef __attribute__((ext_vector_type(4))) float f32x4;

__device__ inline unsigned short f2bf(float x) {
    __hip_bfloat16 h = __float2bfloat16(x);   // RNE
    return *reinterpret_cast<unsigned short*>(&h);
}
__device__ inline float bf2f(unsigned short u) {
    __hip_bfloat16 h = *reinterpret_cast<__hip_bfloat16*>(&u);
    return __bfloat162float(h);
}

// ---------------------------------------------------------------------------
// K1a: t1[i][n][j] = relu( sum_k q[n][k] * W1[i][k][j] )
// grid (NT, 10), block 256.  Each block: one type i, 64-wide j tile, all 32 n.
// Q staged transposed in LDS (stride 33, conflict-free); per-wave ng uniform
// so the 8 q reads per k are LDS broadcasts. 8 independent FMA chains/thread.
__global__ __launch_bounds__(256) void gates1_kernel(
    const float* __restrict__ q,    // (32, 300)
    const float* __restrict__ W1,   // (4, 300, 600)
    float* __restrict__ t1)         // (4, 32, 600)
{
    int i  = blockIdx.x;
    int jt = blockIdx.y;
    int tid = threadIdx.x;
    __shared__ float qT[QD * 33];

    for (int idx = tid; idx < Nn * QD; idx += 256) {
        int n = idx / QD, k = idx - n * QD;
        qT[k * 33 + n] = q[idx];
    }
    __syncthreads();

    int jl = tid & 63, ng = tid >> 6;
    int j = jt * 64 + jl;
    bool jok = (j < 2 * DOUT);
    const float* W1i = W1 + (size_t)i * QD * (2 * DOUT);

    float acc[8];
    #pragma unroll
    for (int r = 0; r < 8; ++r) acc[r] = 0.f;

    #pragma unroll 4
    for (int k = 0; k < QD; ++k) {
        float w = jok ? W1i[(size_t)k * (2 * DOUT) + j] : 0.f;
        const float* qr = &qT[k * 33 + ng * 8];
        #pragma unroll
        for (int r = 0; r < 8; ++r) acc[r] += w * qr[r];
    }

    if (jok) {
        #pragma unroll
        for (int r = 0; r < 8; ++r)
            t1[((size_t)i * Nn + ng * 8 + r) * (2 * DOUT) + j] = fmaxf(acc[r], 0.f);
    }
}

// ---------------------------------------------------------------------------
// K1b: g[i][n][j] = sigmoid( sum_k t1[i][n][k] * W2[i][k][j] )
// grid (NT, 10), block 256. Same structure, K=600.
__global__ __launch_bounds__(256) void gates2_kernel(
    const float* __restrict__ t1,   // (4, 32, 600)
    const float* __restrict__ W2,   // (4, 600, 600)
    float* __restrict__ g)          // (4, 32, 600)
{
    int i  = blockIdx.x;
    int jt = blockIdx.y;
    int tid = threadIdx.x;
    __shared__ float tT[2 * DOUT * 33];   // 600*33*4 = 79.2 KB

    const float* t1i = t1 + (size_t)i * Nn * (2 * DOUT);
    for (int idx = tid; idx < Nn * 2 * DOUT; idx += 256) {
        int n = idx / (2 * DOUT), k = idx - n * (2 * DOUT);
        tT[k * 33 + n] = t1i[idx];
    }
    __syncthreads();

    int jl = tid & 63, ng = tid >> 6;
    int j = jt * 64 + jl;
    bool jok = (j < 2 * DOUT);
    const float* W2i = W2 + (size_t)i * (2 * DOUT) * (2 * DOUT);

    float acc[8];
    #pragma unroll
    for (int r = 0; r < 8; ++r) acc[r] = 0.f;

    #pragma unroll 4
    for (int k = 0; k < 2 * DOUT; ++k) {
        float w = jok ? W2i[(size_t)k * (2 * DOUT) + j] : 0.f;
        const float* tr = &tT[k * 33 + ng * 8];
        #pragma unroll
        for (int r = 0; r < 8; ++r) acc[r] += w * tr[r];
    }

    if (jok) {
        #pragma unroll
        for (int r = 0; r < 8; ++r)
            g[((size_t)i * Nn + ng * 8 + r) * (2 * DOUT) + j] =
                1.f / (1.f + __expf(-acc[r]));
    }
}

// ---------------------------------------------------------------------------
// K2: u1[i][n][k] = sum_d W[i][k][d] * g1[i][n][d] * a1[i][d]  (u2 with g2,a2)
__global__ __launch_bounds__(256) void uvec_kernel(
    const float* __restrict__ W,    // (4, 300, 300)
    const float* __restrict__ a,    // (4, 600)
    const float* __restrict__ g,    // (4, N, 600)
    float* __restrict__ u1,         // (4, N, 300)
    float* __restrict__ u2)         // (4, N, 300)
{
    int i = blockIdx.x;
    int n = blockIdx.y;
    int tid = threadIdx.x;
    __shared__ float w1[DOUT], w2[DOUT];

    const float* gi = g + ((size_t)i * Nn + n) * (2 * DOUT);
    const float* ai = a + (size_t)i * (2 * DOUT);
    for (int d = tid; d < DOUT; d += 256) {
        w1[d] = gi[d] * ai[d];
        w2[d] = gi[DOUT + d] * ai[DOUT + d];
    }
    __syncthreads();

    const float* Wi = W + (size_t)i * DIN * DOUT;
    for (int k = tid; k < DIN; k += 256) {
        float a1 = 0.f, a2 = 0.f;
        for (int d = 0; d < DOUT; ++d) {
            float w = Wi[k * DOUT + d];
            a1 += w * w1[d];
            a2 += w * w2[d];
        }
        u1[((size_t)i * Nn + n) * DIN + k] = a1;
        u2[((size_t)i * Nn + n) * DIN + k] = a2;
    }
}

// ---------------------------------------------------------------------------
// K3: ssrc[i][n][e] = input[n,e,:] . u1[i][n][:]   (sdst with u2)
__global__ __launch_bounds__(64) void sdot_kernel(
    const float* __restrict__ X,    // (N, E, 300)
    const float* __restrict__ u1,   // (4, N, 300)
    const float* __restrict__ u2,   // (4, N, 300)
    float* __restrict__ ssrc,       // (4, N, E)
    float* __restrict__ sdst)       // (4, N, E)
{
    int e = blockIdx.x;
    int n = blockIdx.y;
    int lane = threadIdx.x;
    const float* x = X + ((size_t)n * Ee + e) * DIN;

    float xv[5];
    #pragma unroll
    for (int k = 0; k < 5; ++k) {
        int d = lane + 64 * k;
        xv[k] = (d < DIN) ? x[d] : 0.f;
    }
    #pragma unroll
    for (int i = 0; i < NT; ++i) {
        const float* u1i = u1 + ((size_t)i * Nn + n) * DIN;
        const float* u2i = u2 + ((size_t)i * Nn + n) * DIN;
        float a1 = 0.f, a2 = 0.f;
        #pragma unroll
        for (int k = 0; k < 5; ++k) {
            int d = lane + 64 * k;
            if (d < DIN) { a1 += xv[k] * u1i[d]; a2 += xv[k] * u2i[d]; }
        }
        #pragma unroll
        for (int off = 32; off; off >>= 1) {
            a1 += __shfl_xor(a1, off);
            a2 += __shfl_xor(a2, off);
        }
        if (lane == 0) {
            ssrc[((size_t)i * Nn + n) * Ee + e] = a1;
            sdst[((size_t)i * Nn + n) * Ee + e] = a2;
        }
    }
}

// ---------------------------------------------------------------------------
// K4: hm[row][d] = (X[row,:] @ W3)[d] * mask[row], emitted TRANSPOSED as
// bf16 split pair:  hmT_hi/lo[n][d (pad CPAD)][j],  j = row within batch n.
__global__ __launch_bounds__(256) void hm_kernel(
    const float* __restrict__ X,    // (16384, 300)
    const float* __restrict__ W3,   // (300, 300)
    const float* __restrict__ mask, // (16384)
    unsigned short* __restrict__ hmT_hi,  // (32, CPAD, 512)
    unsigned short* __restrict__ hmT_lo)  // (32, CPAD, 512)
{
    __shared__ float smem[32 * 321];  // phase A: X tile (stride 300); phase B: hm tile (stride 321)
    int tid = threadIdx.x;
    size_t row0 = (size_t)blockIdx.x * 32;

    for (int idx = tid; idx < 32 * DIN; idx += 256)
        smem[idx] = X[row0 * DIN + idx];
    __syncthreads();

    int wv = tid >> 6, lane = tid & 63;
    int r0 = wv * 8;
    float acc[8][5];
    #pragma unroll
    for (int r = 0; r < 8; ++r)
        #pragma unroll
        for (int k = 0; k < 5; ++k) acc[r][k] = 0.f;

    for (int kk = 0; kk < DIN; ++kk) {
        float wval[5];
        #pragma unroll
        for (int k = 0; k < 5; ++k) {
            int d = lane + 64 * k;
            wval[k] = (d < DOUT) ? W3[kk * DOUT + d] : 0.f;
        }
        #pragma unroll
        for (int r = 0; r < 8; ++r) {
            float x = smem[(r0 + r) * DIN + kk];
            #pragma unroll
            for (int k = 0; k < 5; ++k) acc[r][k] += x * wval[k];
        }
    }
    __syncthreads();   // everyone done reading X tile

    // stash hm tile (mask applied, pad cols zeroed) at stride 321
    #pragma unroll
    for (int r = 0; r < 8; ++r) {
        float mk = mask[row0 + r0 + r];
        #pragma unroll
        for (int k = 0; k < 5; ++k) {
            int d = lane + 64 * k;   // 0..319
            smem[(r0 + r) * 321 + d] = (d < DOUT) ? acc[r][k] * mk : 0.f;
        }
    }
    __syncthreads();

    // transposed bf16-split write: lanes along j => coalesced
    int n  = (int)(row0 >> 9);
    int j0 = (int)(row0 & 511);
    int jj = tid & 31;
    for (int dd = tid >> 5; dd < CPAD; dd += 8) {
        float v = smem[jj * 321 + dd];
        unsigned short hi = f2bf(v);
        unsigned short lo = f2bf(v - bf2f(hi));
        size_t off = ((size_t)(n * CPAD + dd)) * Ee + j0 + jj;
        hmT_hi[off] = hi;
        hmT_lo[off] = lo;
    }
}

// ---------------------------------------------------------------------------
// K5: scores -> softmax -> split-bf16 MFMA PV for a 32-row tile of batch n.
// grid: flat 512 blocks with XCD-aware decode: each XCD's private L2 serves
// 4 n-slices of hmT (2.6 MB) for all 16 of their row-tiles.
__global__ __launch_bounds__(256, 2) void attn_kernel(
    const int*   __restrict__ adj,      // (N, E, E)
    const float* __restrict__ ssrc,     // (4, N, E)
    const float* __restrict__ sdst,     // (4, N, E)
    const unsigned short* __restrict__ hmT_hi,  // (32, CPAD, 512)
    const unsigned short* __restrict__ hmT_lo,
    float* __restrict__ out)            // (N, E, 300)
{
    int f  = blockIdx.x;
    int n  = (f & 7) * 4 + ((f >> 3) & 3);   // same-n blocks land on same XCD
    int rt = f >> 5;
    int tid = threadIdx.x;
    int row0 = rt * ROWS;

    __shared__ unsigned coefT[Ee * 33];   // transposed coef [j][r], stride 33
    __shared__ float sdl[NT * Ee];
    __shared__ float ssl[NT * ROWS];

    for (int idx = tid; idx < NT * Ee; idx += 256) {
        int i = idx >> 9, j = idx & (Ee - 1);
        sdl[idx] = sdst[((size_t)i * Nn + n) * Ee + j];
    }
    for (int idx = tid; idx < NT * ROWS; idx += 256) {
        int i = idx >> 5, r = idx & 31;
        ssl[idx] = ssrc[((size_t)i * Nn + n) * Ee + row0 + r];
    }
    __syncthreads();

    // scores (write transposed)
    const int* adjb = adj + ((size_t)n * Ee + row0) * Ee;
    for (int idx = tid; idx < ROWS * Ee; idx += 256) {
        int r = idx >> 9, j = idx & (Ee - 1);
        int t = adjb[idx];
        float v;
        if (t > 0) {
            float x = ssl[(t - 1) * ROWS + r] + sdl[(t - 1) * Ee + j];
            v = (x >= 0.f) ? x : SLOPE * x;
        } else {
            v = -1e30f;
        }
        coefT[j * 33 + r] = __float_as_uint(v);
    }
    __syncthreads();

    // softmax per row (wave w owns rows w*8..w*8+7)
    int wv = tid >> 6, lane = tid & 63;
    #pragma unroll
    for (int rr = 0; rr < 8; ++rr) {
        int r = wv * 8 + rr;
        float vals[8];
        float m = -3.0e38f;
        #pragma unroll
        for (int k = 0; k < 8; ++k) {
            vals[k] = __uint_as_float(coefT[(lane + 64 * k) * 33 + r]);
            m = fmaxf(m, vals[k]);
        }
        #pragma unroll
        for (int off = 32; off; off >>= 1) m = fmaxf(m, __shfl_xor(m, off));
        float s = 0.f;
        #pragma unroll
        for (int k = 0; k < 8; ++k) {
            vals[k] = __expf(vals[k] - m);
            s += vals[k];
        }
        #pragma unroll
        for (int off = 32; off; off >>= 1) s += __shfl_xor(s, off);
        float inv = 1.f / s;
        #pragma unroll
        for (int k = 0; k < 8; ++k)
            coefT[(lane + 64 * k) * 33 + r] = __float_as_uint(vals[k] * inv);
    }
    __syncthreads();

    // pack coef -> (bf16_hi << 16) | bf16_lo, in place
    for (int idx = tid; idx < Ee * ROWS; idx += 256) {
        int j = idx >> 5, r = idx & 31;
        float v = __uint_as_float(coefT[j * 33 + r]);
        unsigned short hi = f2bf(v);
        unsigned short lo = f2bf(v - bf2f(hi));
        coefT[j * 33 + r] = ((unsigned)hi << 16) | (unsigned)lo;
    }
    __syncthreads();

    // PV:  out_tile(32 x 300) = coef(32 x 512) @ hm(512 x 300), split bf16.
    // Wave wv owns n-tiles {wv, wv+4, wv+8, wv+12, wv+16} (CPAD/16 = 20 tiles).
    int g  = lane >> 4;
    int cr = lane & 15;
    f32x4 acc[5][2];
    #pragma unroll
    for (int a = 0; a < 5; ++a)
        #pragma unroll
        for (int m = 0; m < 2; ++m) acc[a][m] = (f32x4){0.f, 0.f, 0.f, 0.f};

    for (int ks = 0; ks < 16; ++ks) {
        int k0 = ks * 32;
        bf16x8 ahi[2], alo[2];
        #pragma unroll
        for (int m = 0; m < 2; ++m) {
            #pragma unroll
            for (int j = 0; j < 8; ++j) {
                unsigned v = coefT[(k0 + 8 * g + j) * 33 + m * 16 + cr];
                ahi[m][j] = (short)(v >> 16);
                alo[m][j] = (short)(v & 0xffffu);
            }
        }
        #pragma unroll
        for (int ntl = 0; ntl < 5; ++ntl) {
            int c = (wv + 4 * ntl) * 16 + cr;
            size_t off = ((size_t)(n * CPAD + c)) * Ee + k0 + 8 * g;
            bf16x8 bhi = *(const bf16x8*)(hmT_hi + off);
            bf16x8 blo = *(const bf16x8*)(hmT_lo + off);
            #pragma unroll
            for (int m = 0; m < 2; ++m) {
                acc[ntl][m] = __builtin_amdgcn_mfma_f32_16x16x32_bf16(ahi[m], bhi, acc[ntl][m], 0, 0, 0);
                acc[ntl][m] = __builtin_amdgcn_mfma_f32_16x16x32_bf16(ahi[m], blo, acc[ntl][m], 0, 0, 0);
                acc[ntl][m] = __builtin_amdgcn_mfma_f32_16x16x32_bf16(alo[m], bhi, acc[ntl][m], 0, 0, 0);
            }
        }
    }

    // epilogue: D[row=4g+q][col=cr] per 16x16 tile
    #pragma unroll
    for (int ntl = 0; ntl < 5; ++ntl) {
        int c = (wv + 4 * ntl) * 16 + cr;
        if (c < DOUT) {
            #pragma unroll
            for (int m = 0; m < 2; ++m) {
                #pragma unroll
                for (int q = 0; q < 4; ++q) {
                    int erow = row0 + m * 16 + 4 * g + q;
                    out[((size_t)n * Ee + erow) * DOUT + c] = acc[ntl][m][q];
                }
            }
        }
    }
}

// ---------------------------------------------------------------------------
extern "C" void kernel_launch(void* const* d_in, const int* in_sizes, int n_in,
                              void* d_out, int out_size, void* d_ws, size_t ws_size,
                              hipStream_t stream) {
    const float* input_state = (const float*)d_in[0];
    const int*   adj         = (const int*)  d_in[1];
    const float* node_mask   = (const float*)d_in[2];
    const float* query_vec   = (const float*)d_in[3];
    const float* W_type      = (const float*)d_in[4];
    const float* a_type      = (const float*)d_in[5];
    const float* qattn_W1    = (const float*)d_in[6];
    const float* qattn_W2    = (const float*)d_in[7];
    float* out = (float*)d_out;

    // workspace layout
    float* ws   = (float*)d_ws;
    float* g    = ws;                 // 4*32*600   = 76800
    float* t1   = g    + 76800;       // 4*32*600   = 76800
    float* u1   = t1   + 76800;       // 4*32*300   = 38400
    float* u2   = u1   + 38400;       // 38400
    float* ssrc = u2   + 38400;       // 4*32*512   = 65536
    float* sdst = ssrc + 65536;       // 65536
    unsigned short* hmT_hi = (unsigned short*)(sdst + 65536);  // 32*320*512 u16
    unsigned short* hmT_lo = hmT_hi + (size_t)Nn * CPAD * Ee;  // 32*320*512 u16

    hipLaunchKernelGGL(gates1_kernel, dim3(NT, 10), dim3(256), 0, stream,
                       query_vec, qattn_W1, t1);
    hipLaunchKernelGGL(gates2_kernel, dim3(NT, 10), dim3(256), 0, stream,
                       t1, qattn_W2, g);
    hipLaunchKernelGGL(uvec_kernel, dim3(NT, Nn), dim3(256), 0, stream,
                       W_type, a_type, g, u1, u2);
    hipLaunchKernelGGL(sdot_kernel, dim3(Ee, Nn), dim3(64), 0, stream,
                       input_state, u1, u2, ssrc, sdst);
    hipLaunchKernelGGL(hm_kernel, dim3((Nn * Ee) / 32), dim3(256), 0, stream,
                       input_state, W_type + 3 * DIN * DOUT, node_mask, hmT_hi, hmT_lo);
    hipLaunchKernelGGL(attn_kernel, dim3(512), dim3(256), 0, stream,
                       adj, ssrc, sdst, hmT_hi, hmT_lo, out);
}

// Round 4
// 276.825 us; speedup vs baseline: 1.0665x; 1.0665x over previous
//
#include <hip/hip_runtime.h>
#include <hip/hip_bf16.h>

// Problem constants
#define Nn   32
#define Ee   512
#define DIN  300
#define DOUT 300
#define NT   4
#define QD   300
#define SLOPE 0.2f
#define ROWS 32   // rows per tile in score/pv kernels
#define CPAD 320  // padded d-dim for hmT (20 MFMA n-tiles of 16)

typedef __attribute__((ext_vector_type(8))) short bf16x8;
typedef __attribute__((ext_vector_type(4))) float f32x4;

__device__ inline unsigned short f2bf(float x) {
    __hip_bfloat16 h = __float2bfloat16(x);   // RNE
    return *reinterpret_cast<unsigned short*>(&h);
}
__device__ inline float bf2f(unsigned short u) {
    __hip_bfloat16 h = *reinterpret_cast<__hip_bfloat16*>(&u);
    return __bfloat162float(h);
}

// ---------------------------------------------------------------------------
// K1a: t1[i][n][j] = relu( sum_k q[n][k] * W1[i][k][j] )
// grid (75, NT), block 256: one thread per (n,j) output. No LDS; q row hits
// L1 (wave-uniform-ish), W column loads coalesced across lanes.
__global__ __launch_bounds__(256) void gates1_kernel(
    const float* __restrict__ q,    // (32, 300)
    const float* __restrict__ W1,   // (4, 300, 600)
    float* __restrict__ t1)         // (4, 32, 600)
{
    int i = blockIdx.y;
    int idx = blockIdx.x * 256 + threadIdx.x;   // 0..19199
    int n = idx / 600, j = idx - n * 600;
    const float* W1i = W1 + (size_t)i * QD * 600;
    const float* qn = q + n * QD;
    float a0 = 0.f, a1 = 0.f;
    #pragma unroll 5
    for (int k = 0; k < QD; k += 2) {
        a0 += qn[k]     * W1i[(size_t)k * 600 + j];
        a1 += qn[k + 1] * W1i[(size_t)(k + 1) * 600 + j];
    }
    t1[((size_t)i * Nn + n) * 600 + j] = fmaxf(a0 + a1, 0.f);
}

// ---------------------------------------------------------------------------
// K1b: g[i][n][j] = sigmoid( sum_k t1[i][n][k] * W2[i][k][j] ), K=600
__global__ __launch_bounds__(256) void gates2_kernel(
    const float* __restrict__ t1,   // (4, 32, 600)
    const float* __restrict__ W2,   // (4, 600, 600)
    float* __restrict__ g)          // (4, 32, 600)
{
    int i = blockIdx.y;
    int idx = blockIdx.x * 256 + threadIdx.x;
    int n = idx / 600, j = idx - n * 600;
    const float* W2i = W2 + (size_t)i * 600 * 600;
    const float* tn = t1 + ((size_t)i * Nn + n) * 600;
    float a0 = 0.f, a1 = 0.f;
    #pragma unroll 5
    for (int k = 0; k < 600; k += 2) {
        a0 += tn[k]     * W2i[(size_t)k * 600 + j];
        a1 += tn[k + 1] * W2i[(size_t)(k + 1) * 600 + j];
    }
    g[((size_t)i * Nn + n) * 600 + j] = 1.f / (1.f + __expf(-(a0 + a1)));
}

// ---------------------------------------------------------------------------
// K2: u1[i][n][k] = sum_d W[i][k][d] * g1[i][n][d] * a1[i][d]  (u2 with g2,a2)
// grid (NT, Nn, 8), block 64 (single wave): k-chunk of 38 per block.
// W row reads coalesced across lanes; w-vectors staged in LDS.
__global__ __launch_bounds__(64) void uvec_kernel(
    const float* __restrict__ W,    // (4, 300, 300)
    const float* __restrict__ a,    // (4, 600)
    const float* __restrict__ g,    // (4, N, 600)
    float* __restrict__ u1,         // (4, N, 300)
    float* __restrict__ u2)         // (4, N, 300)
{
    int i = blockIdx.x, n = blockIdx.y, kt = blockIdx.z;
    int lane = threadIdx.x;
    __shared__ float w1[DOUT], w2[DOUT];

    const float* gi = g + ((size_t)i * Nn + n) * 600;
    const float* ai = a + (size_t)i * 600;
    for (int d = lane; d < DOUT; d += 64) {
        w1[d] = gi[d] * ai[d];
        w2[d] = gi[DOUT + d] * ai[DOUT + d];
    }
    __syncthreads();

    int k0 = kt * 38;
    int k1 = k0 + 38 < DIN ? k0 + 38 : DIN;
    const float* Wi = W + (size_t)i * DIN * DOUT;
    for (int k = k0; k < k1; ++k) {
        const float* Wk = Wi + (size_t)k * DOUT;
        float s1 = 0.f, s2 = 0.f;
        #pragma unroll
        for (int c = 0; c < 5; ++c) {
            int d = lane + 64 * c;
            if (d < DOUT) { float w = Wk[d]; s1 += w * w1[d]; s2 += w * w2[d]; }
        }
        #pragma unroll
        for (int off = 32; off; off >>= 1) {
            s1 += __shfl_xor(s1, off);
            s2 += __shfl_xor(s2, off);
        }
        if (lane == 0) {
            u1[((size_t)i * Nn + n) * DIN + k] = s1;
            u2[((size_t)i * Nn + n) * DIN + k] = s2;
        }
    }
}

// ---------------------------------------------------------------------------
// K4: hm = (X @ W3) * mask  -> transposed bf16-split hmT planes,
// PLUS fused sdot: ssrc/sdst[i][n][e] = X[n,e,:] . u1/u2[i][n][:]
// (reuses the staged X tile; saves a full 19.7MB X re-read).
__global__ __launch_bounds__(256) void hm_sdot_kernel(
    const float* __restrict__ X,    // (16384, 300)
    const float* __restrict__ W3,   // (300, 300)
    const float* __restrict__ mask, // (16384)
    const float* __restrict__ u1,   // (4, 32, 300)
    const float* __restrict__ u2,   // (4, 32, 300)
    unsigned short* __restrict__ hmT_hi,  // (32, CPAD, 512)
    unsigned short* __restrict__ hmT_lo,  // (32, CPAD, 512)
    float* __restrict__ ssrc,       // (4, 32, 512)
    float* __restrict__ sdst)       // (4, 32, 512)
{
    __shared__ float smem[32 * 321];  // phase A: X tile (stride 300); later: hm tile (stride 321)
    __shared__ float uL[NT * 2 * DOUT];  // [i*600 + d] = u1, [i*600+300+d] = u2
    int tid = threadIdx.x;
    size_t row0 = (size_t)blockIdx.x * 32;
    int n  = (int)(row0 >> 9);
    int j0 = (int)(row0 & 511);

    for (int idx = tid; idx < 32 * DIN; idx += 256)
        smem[idx] = X[row0 * DIN + idx];
    for (int idx = tid; idx < NT * 2 * DOUT; idx += 256) {
        int i = idx / 600, r = idx - i * 600;
        uL[idx] = (r < DOUT) ? u1[((size_t)i * Nn + n) * DIN + r]
                             : u2[((size_t)i * Nn + n) * DIN + (r - DOUT)];
    }
    __syncthreads();

    int wv = tid >> 6, lane = tid & 63;
    int r0 = wv * 8;
    float acc[8][5];
    #pragma unroll
    for (int r = 0; r < 8; ++r)
        #pragma unroll
        for (int k = 0; k < 5; ++k) acc[r][k] = 0.f;

    for (int kk = 0; kk < DIN; ++kk) {
        float wval[5];
        #pragma unroll
        for (int k = 0; k < 5; ++k) {
            int d = lane + 64 * k;
            wval[k] = (d < DOUT) ? W3[kk * DOUT + d] : 0.f;
        }
        #pragma unroll
        for (int r = 0; r < 8; ++r) {
            float x = smem[(r0 + r) * DIN + kk];
            #pragma unroll
            for (int k = 0; k < 5; ++k) acc[r][k] += x * wval[k];
        }
    }

    // ---- fused sdot: wave wv handles local rows r0..r0+7 ----
    #pragma unroll
    for (int rr = 0; rr < 8; ++rr) {
        int le = r0 + rr;
        float xv[5];
        #pragma unroll
        for (int c = 0; c < 5; ++c) {
            int d = lane + 64 * c;
            xv[c] = (d < DIN) ? smem[le * DIN + d] : 0.f;
        }
        float s[8];
        #pragma unroll
        for (int i = 0; i < NT; ++i) {
            float s1 = 0.f, s2 = 0.f;
            #pragma unroll
            for (int c = 0; c < 5; ++c) {
                int d = lane + 64 * c;
                if (d < DIN) {
                    s1 += xv[c] * uL[i * 600 + d];
                    s2 += xv[c] * uL[i * 600 + DOUT + d];
                }
            }
            s[2 * i] = s1; s[2 * i + 1] = s2;
        }
        #pragma unroll
        for (int off = 32; off; off >>= 1) {
            #pragma unroll
            for (int v = 0; v < 8; ++v) s[v] += __shfl_xor(s[v], off);
        }
        if (lane == 0) {
            #pragma unroll
            for (int i = 0; i < NT; ++i) {
                ssrc[((size_t)i * Nn + n) * Ee + j0 + le] = s[2 * i];
                sdst[((size_t)i * Nn + n) * Ee + j0 + le] = s[2 * i + 1];
            }
        }
    }
    __syncthreads();   // everyone done reading X tile

    // stash hm tile (mask applied, pad cols zeroed) at stride 321
    #pragma unroll
    for (int r = 0; r < 8; ++r) {
        float mk = mask[row0 + r0 + r];
        #pragma unroll
        for (int k = 0; k < 5; ++k) {
            int d = lane + 64 * k;   // 0..319
            smem[(r0 + r) * 321 + d] = (d < DOUT) ? acc[r][k] * mk : 0.f;
        }
    }
    __syncthreads();

    // transposed bf16-split write: lanes along j => coalesced
    int jj = tid & 31;
    for (int dd = tid >> 5; dd < CPAD; dd += 8) {
        float v = smem[jj * 321 + dd];
        unsigned short hi = f2bf(v);
        unsigned short lo = f2bf(v - bf2f(hi));
        size_t off = ((size_t)(n * CPAD + dd)) * Ee + j0 + jj;
        hmT_hi[off] = hi;
        hmT_lo[off] = lo;
    }
}

// ---------------------------------------------------------------------------
// K5a: scores -> softmax -> pack -> A-fragment store (hi/lo planes, PV order).
// grid 512 flat (XCD decode), block 256.
__global__ __launch_bounds__(256, 2) void score_kernel(
    const int*   __restrict__ adj,      // (N, E, E)
    const float* __restrict__ ssrc,     // (4, N, E)
    const float* __restrict__ sdst,     // (4, N, E)
    unsigned short* __restrict__ AH,    // (512 tiles, 16 ks, 2 m, 64 lane, 8)
    unsigned short* __restrict__ AL)
{
    int f  = blockIdx.x;
    int n  = (f & 7) * 4 + ((f >> 3) & 3);
    int rt = f >> 5;
    int tid = threadIdx.x;
    int row0 = rt * ROWS;

    __shared__ unsigned coefT[Ee * 33];   // transposed coef [j][r], stride 33
    __shared__ float sdl[NT * Ee];
    __shared__ float ssl[NT * ROWS];

    for (int idx = tid; idx < NT * Ee; idx += 256) {
        int i = idx >> 9, j = idx & (Ee - 1);
        sdl[idx] = sdst[((size_t)i * Nn + n) * Ee + j];
    }
    for (int idx = tid; idx < NT * ROWS; idx += 256) {
        int i = idx >> 5, r = idx & 31;
        ssl[idx] = ssrc[((size_t)i * Nn + n) * Ee + row0 + r];
    }
    __syncthreads();

    const int* adjb = adj + ((size_t)n * Ee + row0) * Ee;
    for (int idx = tid; idx < ROWS * Ee; idx += 256) {
        int r = idx >> 9, j = idx & (Ee - 1);
        int t = adjb[idx];
        float v;
        if (t > 0) {
            float x = ssl[(t - 1) * ROWS + r] + sdl[(t - 1) * Ee + j];
            v = (x >= 0.f) ? x : SLOPE * x;
        } else {
            v = -1e30f;
        }
        coefT[j * 33 + r] = __float_as_uint(v);
    }
    __syncthreads();

    // softmax per row
    int wv = tid >> 6, lane = tid & 63;
    #pragma unroll
    for (int rr = 0; rr < 8; ++rr) {
        int r = wv * 8 + rr;
        float vals[8];
        float m = -3.0e38f;
        #pragma unroll
        for (int k = 0; k < 8; ++k) {
            vals[k] = __uint_as_float(coefT[(lane + 64 * k) * 33 + r]);
            m = fmaxf(m, vals[k]);
        }
        #pragma unroll
        for (int off = 32; off; off >>= 1) m = fmaxf(m, __shfl_xor(m, off));
        float s = 0.f;
        #pragma unroll
        for (int k = 0; k < 8; ++k) {
            vals[k] = __expf(vals[k] - m);
            s += vals[k];
        }
        #pragma unroll
        for (int off = 32; off; off >>= 1) s += __shfl_xor(s, off);
        float inv = 1.f / s;
        #pragma unroll
        for (int k = 0; k < 8; ++k)
            coefT[(lane + 64 * k) * 33 + r] = __float_as_uint(vals[k] * inv);
    }
    __syncthreads();

    // pack coef -> (bf16_hi << 16) | bf16_lo, in place
    for (int idx = tid; idx < Ee * ROWS; idx += 256) {
        int j = idx >> 5, r = idx & 31;
        float v = __uint_as_float(coefT[j * 33 + r]);
        unsigned short hi = f2bf(v);
        unsigned short lo = f2bf(v - bf2f(hi));
        coefT[j * 33 + r] = ((unsigned)hi << 16) | (unsigned)lo;
    }
    __syncthreads();

    // A-fragment store: task t = ks*128 + m*64 + lane_, 8 tasks/thread.
    size_t tbase = ((size_t)(n * 16 + rt)) * 2048 * 8;
    for (int t = tid; t < 2048; t += 256) {
        int ks = t >> 7, rem = t & 127, m = rem >> 6, ln = rem & 63;
        int g2 = ln >> 4, cr2 = ln & 15;
        int k0 = ks * 32;
        bf16x8 hv, lv;
        #pragma unroll
        for (int jp = 0; jp < 8; ++jp) {
            unsigned w = coefT[(k0 + 8 * g2 + jp) * 33 + m * 16 + cr2];
            hv[jp] = (short)(w >> 16);
            lv[jp] = (short)(w & 0xffffu);
        }
        size_t o = tbase + (size_t)t * 8;
        *(bf16x8*)(AH + o) = hv;
        *(bf16x8*)(AL + o) = lv;
    }
}

// ---------------------------------------------------------------------------
// K5b: PV GEMM from pre-formatted fragments. No LDS, no barriers.
// grid 512 flat (same XCD decode), block 256.
__global__ __launch_bounds__(256) void pv_kernel(
    const unsigned short* __restrict__ AH,
    const unsigned short* __restrict__ AL,
    const unsigned short* __restrict__ hmT_hi,  // (32, CPAD, 512)
    const unsigned short* __restrict__ hmT_lo,
    float* __restrict__ out)            // (N, E, 300)
{
    int f  = blockIdx.x;
    int n  = (f & 7) * 4 + ((f >> 3) & 3);
    int rt = f >> 5;
    int tid = threadIdx.x, wv = tid >> 6, lane = tid & 63;
    int g = lane >> 4, cr = lane & 15;
    int row0 = rt * ROWS;
    size_t tbase = ((size_t)(n * 16 + rt)) * 2048 * 8;

    f32x4 acc[5][2];
    #pragma unroll
    for (int a = 0; a < 5; ++a)
        #pragma unroll
        for (int m = 0; m < 2; ++m) acc[a][m] = (f32x4){0.f, 0.f, 0.f, 0.f};

    for (int ks = 0; ks < 16; ++ks) {
        bf16x8 ahi[2], alo[2];
        #pragma unroll
        for (int m = 0; m < 2; ++m) {
            size_t o = tbase + (size_t)((ks * 2 + m) * 64 + lane) * 8;
            ahi[m] = *(const bf16x8*)(AH + o);
            alo[m] = *(const bf16x8*)(AL + o);
        }
        int k0 = ks * 32;
        #pragma unroll
        for (int ntl = 0; ntl < 5; ++ntl) {
            int c = (wv + 4 * ntl) * 16 + cr;
            size_t off = ((size_t)(n * CPAD + c)) * Ee + k0 + 8 * g;
            bf16x8 bhi = *(const bf16x8*)(hmT_hi + off);
            bf16x8 blo = *(const bf16x8*)(hmT_lo + off);
            #pragma unroll
            for (int m = 0; m < 2; ++m) {
                acc[ntl][m] = __builtin_amdgcn_mfma_f32_16x16x32_bf16(ahi[m], bhi, acc[ntl][m], 0, 0, 0);
                acc[ntl][m] = __builtin_amdgcn_mfma_f32_16x16x32_bf16(ahi[m], blo, acc[ntl][m], 0, 0, 0);
                acc[ntl][m] = __builtin_amdgcn_mfma_f32_16x16x32_bf16(alo[m], bhi, acc[ntl][m], 0, 0, 0);
            }
        }
    }

    #pragma unroll
    for (int ntl = 0; ntl < 5; ++ntl) {
        int c = (wv + 4 * ntl) * 16 + cr;
        if (c < DOUT) {
            #pragma unroll
            for (int m = 0; m < 2; ++m) {
                #pragma unroll
                for (int q = 0; q < 4; ++q) {
                    int erow = row0 + m * 16 + 4 * g + q;
                    out[((size_t)n * Ee + erow) * DOUT + c] = acc[ntl][m][q];
                }
            }
        }
    }
}

// ---------------------------------------------------------------------------
// Fallback: fused scores->softmax->PV (used only if ws too small for split).
__global__ __launch_bounds__(256, 2) void attn_kernel(
    const int*   __restrict__ adj,
    const float* __restrict__ ssrc,
    const float* __restrict__ sdst,
    const unsigned short* __restrict__ hmT_hi,
    const unsigned short* __restrict__ hmT_lo,
    float* __restrict__ out)
{
    int f  = blockIdx.x;
    int n  = (f & 7) * 4 + ((f >> 3) & 3);
    int rt = f >> 5;
    int tid = threadIdx.x;
    int row0 = rt * ROWS;

    __shared__ unsigned coefT[Ee * 33];
    __shared__ float sdl[NT * Ee];
    __shared__ float ssl[NT * ROWS];

    for (int idx = tid; idx < NT * Ee; idx += 256) {
        int i = idx >> 9, j = idx & (Ee - 1);
        sdl[idx] = sdst[((size_t)i * Nn + n) * Ee + j];
    }
    for (int idx = tid; idx < NT * ROWS; idx += 256) {
        int i = idx >> 5, r = idx & 31;
        ssl[idx] = ssrc[((size_t)i * Nn + n) * Ee + row0 + r];
    }
    __syncthreads();

    const int* adjb = adj + ((size_t)n * Ee + row0) * Ee;
    for (int idx = tid; idx < ROWS * Ee; idx += 256) {
        int r = idx >> 9, j = idx & (Ee - 1);
        int t = adjb[idx];
        float v;
        if (t > 0) {
            float x = ssl[(t - 1) * ROWS + r] + sdl[(t - 1) * Ee + j];
            v = (x >= 0.f) ? x : SLOPE * x;
        } else {
            v = -1e30f;
        }
        coefT[j * 33 + r] = __float_as_uint(v);
    }
    __syncthreads();

    int wv = tid >> 6, lane = tid & 63;
    #pragma unroll
    for (int rr = 0; rr < 8; ++rr) {
        int r = wv * 8 + rr;
        float vals[8];
        float m = -3.0e38f;
        #pragma unroll
        for (int k = 0; k < 8; ++k) {
            vals[k] = __uint_as_float(coefT[(lane + 64 * k) * 33 + r]);
            m = fmaxf(m, vals[k]);
        }
        #pragma unroll
        for (int off = 32; off; off >>= 1) m = fmaxf(m, __shfl_xor(m, off));
        float s = 0.f;
        #pragma unroll
        for (int k = 0; k < 8; ++k) {
            vals[k] = __expf(vals[k] - m);
            s += vals[k];
        }
        #pragma unroll
        for (int off = 32; off; off >>= 1) s += __shfl_xor(s, off);
        float inv = 1.f / s;
        #pragma unroll
        for (int k = 0; k < 8; ++k)
            coefT[(lane + 64 * k) * 33 + r] = __float_as_uint(vals[k] * inv);
    }
    __syncthreads();

    for (int idx = tid; idx < Ee * ROWS; idx += 256) {
        int j = idx >> 5, r = idx & 31;
        float v = __uint_as_float(coefT[j * 33 + r]);
        unsigned short hi = f2bf(v);
        unsigned short lo = f2bf(v - bf2f(hi));
        coefT[j * 33 + r] = ((unsigned)hi << 16) | (unsigned)lo;
    }
    __syncthreads();

    int g = lane >> 4;
    int cr = lane & 15;
    f32x4 acc[5][2];
    #pragma unroll
    for (int a = 0; a < 5; ++a)
        #pragma unroll
        for (int m = 0; m < 2; ++m) acc[a][m] = (f32x4){0.f, 0.f, 0.f, 0.f};

    for (int ks = 0; ks < 16; ++ks) {
        int k0 = ks * 32;
        bf16x8 ahi[2], alo[2];
        #pragma unroll
        for (int m = 0; m < 2; ++m) {
            #pragma unroll
            for (int j = 0; j < 8; ++j) {
                unsigned v = coefT[(k0 + 8 * g + j) * 33 + m * 16 + cr];
                ahi[m][j] = (short)(v >> 16);
                alo[m][j] = (short)(v & 0xffffu);
            }
        }
        #pragma unroll
        for (int ntl = 0; ntl < 5; ++ntl) {
            int c = (wv + 4 * ntl) * 16 + cr;
            size_t off = ((size_t)(n * CPAD + c)) * Ee + k0 + 8 * g;
            bf16x8 bhi = *(const bf16x8*)(hmT_hi + off);
            bf16x8 blo = *(const bf16x8*)(hmT_lo + off);
            #pragma unroll
            for (int m = 0; m < 2; ++m) {
                acc[ntl][m] = __builtin_amdgcn_mfma_f32_16x16x32_bf16(ahi[m], bhi, acc[ntl][m], 0, 0, 0);
                acc[ntl][m] = __builtin_amdgcn_mfma_f32_16x16x32_bf16(ahi[m], blo, acc[ntl][m], 0, 0, 0);
                acc[ntl][m] = __builtin_amdgcn_mfma_f32_16x16x32_bf16(alo[m], bhi, acc[ntl][m], 0, 0, 0);
            }
        }
    }

    #pragma unroll
    for (int ntl = 0; ntl < 5; ++ntl) {
        int c = (wv + 4 * ntl) * 16 + cr;
        if (c < DOUT) {
            #pragma unroll
            for (int m = 0; m < 2; ++m) {
                #pragma unroll
                for (int q = 0; q < 4; ++q) {
                    int erow = row0 + m * 16 + 4 * g + q;
                    out[((size_t)n * Ee + erow) * DOUT + c] = acc[ntl][m][q];
                }
            }
        }
    }
}

// ---------------------------------------------------------------------------
extern "C" void kernel_launch(void* const* d_in, const int* in_sizes, int n_in,
                              void* d_out, int out_size, void* d_ws, size_t ws_size,
                              hipStream_t stream) {
    const float* input_state = (const float*)d_in[0];
    const int*   adj         = (const int*)  d_in[1];
    const float* node_mask   = (const float*)d_in[2];
    const float* query_vec   = (const float*)d_in[3];
    const float* W_type      = (const float*)d_in[4];
    const float* a_type      = (const float*)d_in[5];
    const float* qattn_W1    = (const float*)d_in[6];
    const float* qattn_W2    = (const float*)d_in[7];
    float* out = (float*)d_out;

    // workspace layout
    float* ws   = (float*)d_ws;
    float* g    = ws;                 // 4*32*600   = 76800
    float* t1   = g    + 76800;       // 76800
    float* u1   = t1   + 76800;       // 38400
    float* u2   = u1   + 38400;       // 38400
    float* ssrc = u2   + 38400;       // 65536
    float* sdst = ssrc + 65536;       // 65536
    unsigned short* hmT_hi = (unsigned short*)(sdst + 65536);  // 5,242,880 u16
    unsigned short* hmT_lo = hmT_hi + (size_t)Nn * CPAD * Ee;
    unsigned short* AH = hmT_lo + (size_t)Nn * CPAD * Ee;      // 8,388,608 u16
    unsigned short* AL = AH + (size_t)512 * 2048 * 8;

    size_t need_split = (size_t)((char*)(AL + (size_t)512 * 2048 * 8) - (char*)d_ws);
    bool use_split = ws_size >= need_split;

    hipLaunchKernelGGL(gates1_kernel, dim3(75, NT), dim3(256), 0, stream,
                       query_vec, qattn_W1, t1);
    hipLaunchKernelGGL(gates2_kernel, dim3(75, NT), dim3(256), 0, stream,
                       t1, qattn_W2, g);
    hipLaunchKernelGGL(uvec_kernel, dim3(NT, Nn, 8), dim3(64), 0, stream,
                       W_type, a_type, g, u1, u2);
    hipLaunchKernelGGL(hm_sdot_kernel, dim3((Nn * Ee) / 32), dim3(256), 0, stream,
                       input_state, W_type + 3 * DIN * DOUT, node_mask,
                       u1, u2, hmT_hi, hmT_lo, ssrc, sdst);
    if (use_split) {
        hipLaunchKernelGGL(score_kernel, dim3(512), dim3(256), 0, stream,
                           adj, ssrc, sdst, AH, AL);
        hipLaunchKernelGGL(pv_kernel, dim3(512), dim3(256), 0, stream,
                           AH, AL, hmT_hi, hmT_lo, out);
    } else {
        hipLaunchKernelGGL(attn_kernel, dim3(512), dim3(256), 0, stream,
                           adj, ssrc, sdst, hmT_hi, hmT_lo, out);
    }
}

// Round 6
// 229.841 us; speedup vs baseline: 1.2845x; 1.2044x over previous
//
#include <hip/hip_runtime.h>
#include <hip/hip_bf16.h>

// Problem constants
#define Nn   32
#define Ee   512
#define DIN  300
#define DOUT 300
#define NT   4
#define QD   300
#define SLOPE 0.2f
#define ROWS 32   // rows per tile in score/pv kernels
#define CPAD 320  // padded d-dim for hmT (20 MFMA n-tiles of 16)

typedef __attribute__((ext_vector_type(8))) short bf16x8;
typedef __attribute__((ext_vector_type(4))) float f32x4;
typedef __attribute__((ext_vector_type(4))) unsigned short u16x4;

__device__ inline unsigned short f2bf(float x) {
    __hip_bfloat16 h = __float2bfloat16(x);   // RNE
    return *reinterpret_cast<unsigned short*>(&h);
}
__device__ inline float bf2f(unsigned short u) {
    __hip_bfloat16 h = *reinterpret_cast<__hip_bfloat16*>(&u);
    return __bfloat162float(h);
}

// ---------------------------------------------------------------------------
// K0: prep. W3T split planes [c=320][k=320] (W3T[c][k] = W3[k][c], pad 0),
// and zero UT planes [32][16][320].
__global__ __launch_bounds__(256) void prep_kernel(
    const float* __restrict__ W3,          // (300, 300)  row k, col d
    unsigned short* __restrict__ W3T_hi,   // (320, 320)
    unsigned short* __restrict__ W3T_lo,
    unsigned short* __restrict__ UTh,      // (32, 16, 320)
    unsigned short* __restrict__ UTl)
{
    int idx = blockIdx.x * 256 + threadIdx.x;   // grid 640 -> 163840 threads
    if (idx < 320 * 320) {
        int c = idx / 320, k = idx - c * 320;
        float v = (c < DOUT && k < DIN) ? W3[(size_t)k * DOUT + c] : 0.f;
        unsigned short h = f2bf(v);
        W3T_hi[idx] = h;
        W3T_lo[idx] = f2bf(v - bf2f(h));
    }
    if (idx < 32 * 16 * 320) { UTh[idx] = 0; UTl[idx] = 0; }
}

// ---------------------------------------------------------------------------
// K1a: t1[i][n][j] = relu( sum_k q[n][k] * W1[i][k][j] )
__global__ __launch_bounds__(256) void gates1_kernel(
    const float* __restrict__ q,    // (32, 300)
    const float* __restrict__ W1,   // (4, 300, 600)
    float* __restrict__ t1)         // (4, 32, 600)
{
    int i = blockIdx.y;
    int idx = blockIdx.x * 256 + threadIdx.x;   // 0..19199
    int n = idx / 600, j = idx - n * 600;
    const float* W1i = W1 + (size_t)i * QD * 600;
    const float* qn = q + n * QD;
    float a0 = 0.f, a1 = 0.f;
    #pragma unroll 5
    for (int k = 0; k < QD; k += 2) {
        a0 += qn[k]     * W1i[(size_t)k * 600 + j];
        a1 += qn[k + 1] * W1i[(size_t)(k + 1) * 600 + j];
    }
    t1[((size_t)i * Nn + n) * 600 + j] = fmaxf(a0 + a1, 0.f);
}

// ---------------------------------------------------------------------------
// K1b: g[i][n][j] = sigmoid( sum_k t1[i][n][k] * W2[i][k][j] ), K=600
__global__ __launch_bounds__(256) void gates2_kernel(
    const float* __restrict__ t1,   // (4, 32, 600)
    const float* __restrict__ W2,   // (4, 600, 600)
    float* __restrict__ g)          // (4, 32, 600)
{
    int i = blockIdx.y;
    int idx = blockIdx.x * 256 + threadIdx.x;
    int n = idx / 600, j = idx - n * 600;
    const float* W2i = W2 + (size_t)i * 600 * 600;
    const float* tn = t1 + ((size_t)i * Nn + n) * 600;
    float a0 = 0.f, a1 = 0.f;
    #pragma unroll 5
    for (int k = 0; k < 600; k += 2) {
        a0 += tn[k]     * W2i[(size_t)k * 600 + j];
        a1 += tn[k + 1] * W2i[(size_t)(k + 1) * 600 + j];
    }
    g[((size_t)i * Nn + n) * 600 + j] = 1.f / (1.f + __expf(-(a0 + a1)));
}

// ---------------------------------------------------------------------------
// K2: u-vectors -> bf16-split UT planes.
// UT row c=2i -> u1[i] (for ssrc), c=2i+1 -> u2[i] (for sdst). Rows 8..15 and
// k>=300 stay zero (prep_kernel).
__global__ __launch_bounds__(64) void uvec_kernel(
    const float* __restrict__ W,    // (4, 300, 300)
    const float* __restrict__ a,    // (4, 600)
    const float* __restrict__ g,    // (4, N, 600)
    unsigned short* __restrict__ UTh,  // (32, 16, 320)
    unsigned short* __restrict__ UTl)
{
    int i = blockIdx.x, n = blockIdx.y, kt = blockIdx.z;
    int lane = threadIdx.x;
    __shared__ float w1[DOUT], w2[DOUT];

    const float* gi = g + ((size_t)i * Nn + n) * 600;
    const float* ai = a + (size_t)i * 600;
    for (int d = lane; d < DOUT; d += 64) {
        w1[d] = gi[d] * ai[d];
        w2[d] = gi[DOUT + d] * ai[DOUT + d];
    }
    __syncthreads();

    int k0 = kt * 38;
    int k1 = k0 + 38 < DIN ? k0 + 38 : DIN;
    const float* Wi = W + (size_t)i * DIN * DOUT;
    for (int k = k0; k < k1; ++k) {
        const float* Wk = Wi + (size_t)k * DOUT;
        float s1 = 0.f, s2 = 0.f;
        #pragma unroll
        for (int c = 0; c < 5; ++c) {
            int d = lane + 64 * c;
            if (d < DOUT) { float w = Wk[d]; s1 += w * w1[d]; s2 += w * w2[d]; }
        }
        #pragma unroll
        for (int off = 32; off; off >>= 1) {
            s1 += __shfl_xor(s1, off);
            s2 += __shfl_xor(s2, off);
        }
        if (lane == 0) {
            unsigned short h1 = f2bf(s1), l1 = f2bf(s1 - bf2f(h1));
            unsigned short h2 = f2bf(s2), l2 = f2bf(s2 - bf2f(h2));
            size_t b = ((size_t)n * 16 + 2 * i) * 320 + k;
            UTh[b] = h1;       UTl[b] = l1;
            UTh[b + 320] = h2; UTl[b + 320] = l2;
        }
    }
}

// ---------------------------------------------------------------------------
// K4: MFMA hm GEMM + fused sdot.
// Per block: 32 X-rows. A-frags straight from global X (float4 pairs),
// split to bf16 hi/lo in-register. B = W3T planes (k-contiguous 16B loads).
// Wave wv owns hm n-tiles {wv,wv+4,...,wv+16}; wave 0 additionally computes
// the sdot tile (B = UT planes).
__global__ __launch_bounds__(256) void hm_mfma_kernel(
    const float* __restrict__ X,               // (16384, 300)
    const float* __restrict__ mask,            // (16384)
    const unsigned short* __restrict__ W3T_hi, // (320, 320)
    const unsigned short* __restrict__ W3T_lo,
    const unsigned short* __restrict__ UTh,    // (32, 16, 320)
    const unsigned short* __restrict__ UTl,
    unsigned short* __restrict__ hmT_hi,       // (32, CPAD, 512)
    unsigned short* __restrict__ hmT_lo,
    float* __restrict__ ssrc,                  // (4, 32, 512)
    float* __restrict__ sdst)
{
    int tid = threadIdx.x, wv = tid >> 6, lane = tid & 63;
    int g = lane >> 4, cr = lane & 15;
    size_t row0 = (size_t)blockIdx.x * 32;
    int n = (int)(row0 >> 9), j0 = (int)(row0 & 511);

    __shared__ float maskL[32];
    if (tid < 32) maskL[tid] = mask[row0 + tid];
    __syncthreads();

    f32x4 acc[5][2];
    f32x4 sacc[2];
    #pragma unroll
    for (int a = 0; a < 5; ++a)
        #pragma unroll
        for (int m = 0; m < 2; ++m) acc[a][m] = (f32x4){0.f, 0.f, 0.f, 0.f};
    sacc[0] = (f32x4){0.f, 0.f, 0.f, 0.f};
    sacc[1] = (f32x4){0.f, 0.f, 0.f, 0.f};

    const float* xr0 = X + (row0 + cr) * DIN;        // m=0 row
    const float* xr1 = X + (row0 + 16 + cr) * DIN;   // m=1 row

    for (int ks = 0; ks < 10; ++ks) {
        int k0 = ks * 32 + 8 * g;     // per-lane k base
        bf16x8 ahi[2], alo[2];
        #pragma unroll
        for (int m = 0; m < 2; ++m) {
            const float* xr = m ? xr1 : xr0;
            float x8[8];
            if (ks < 9) {
                f32x4 v0 = *(const f32x4*)(xr + k0);
                f32x4 v1 = *(const f32x4*)(xr + k0 + 4);
                #pragma unroll
                for (int j = 0; j < 4; ++j) { x8[j] = v0[j]; x8[4 + j] = v1[j]; }
            } else {
                #pragma unroll
                for (int j = 0; j < 8; ++j) {
                    int k = k0 + j;
                    x8[j] = (k < DIN) ? xr[k] : 0.f;
                }
            }
            #pragma unroll
            for (int j = 0; j < 8; ++j) {
                unsigned short h = f2bf(x8[j]);
                ahi[m][j] = (short)h;
                alo[m][j] = (short)f2bf(x8[j] - bf2f(h));
            }
        }
        #pragma unroll
        for (int ntl = 0; ntl < 5; ++ntl) {
            int c = (wv + 4 * ntl) * 16 + cr;
            bf16x8 bh = *(const bf16x8*)(W3T_hi + (size_t)c * 320 + k0);
            bf16x8 bl = *(const bf16x8*)(W3T_lo + (size_t)c * 320 + k0);
            #pragma unroll
            for (int m = 0; m < 2; ++m) {
                acc[ntl][m] = __builtin_amdgcn_mfma_f32_16x16x32_bf16(ahi[m], bh, acc[ntl][m], 0, 0, 0);
                acc[ntl][m] = __builtin_amdgcn_mfma_f32_16x16x32_bf16(ahi[m], bl, acc[ntl][m], 0, 0, 0);
                acc[ntl][m] = __builtin_amdgcn_mfma_f32_16x16x32_bf16(alo[m], bh, acc[ntl][m], 0, 0, 0);
            }
        }
        if (wv == 0) {
            bf16x8 uh = *(const bf16x8*)(UTh + ((size_t)n * 16 + cr) * 320 + k0);
            bf16x8 ul = *(const bf16x8*)(UTl + ((size_t)n * 16 + cr) * 320 + k0);
            #pragma unroll
            for (int m = 0; m < 2; ++m) {
                sacc[m] = __builtin_amdgcn_mfma_f32_16x16x32_bf16(ahi[m], uh, sacc[m], 0, 0, 0);
                sacc[m] = __builtin_amdgcn_mfma_f32_16x16x32_bf16(ahi[m], ul, sacc[m], 0, 0, 0);
                sacc[m] = __builtin_amdgcn_mfma_f32_16x16x32_bf16(alo[m], uh, sacc[m], 0, 0, 0);
            }
        }
    }

    // hm epilogue: mask, split, transposed store (q contiguous in j -> 8B)
    #pragma unroll
    for (int ntl = 0; ntl < 5; ++ntl) {
        int c = (wv + 4 * ntl) * 16 + cr;
        #pragma unroll
        for (int m = 0; m < 2; ++m) {
            u16x4 h4, l4;
            #pragma unroll
            for (int qq = 0; qq < 4; ++qq) {
                float v = acc[ntl][m][qq] * maskL[m * 16 + 4 * g + qq];
                unsigned short h = f2bf(v);
                h4[qq] = h;
                l4[qq] = f2bf(v - bf2f(h));
            }
            size_t off = ((size_t)(n * CPAD + c)) * Ee + j0 + m * 16 + 4 * g;
            *(u16x4*)(hmT_hi + off) = h4;
            *(u16x4*)(hmT_lo + off) = l4;
        }
    }

    // sdot epilogue: D[row][c], c=2i -> ssrc, c=2i+1 -> sdst
    if (wv == 0 && cr < 8) {
        int i = cr >> 1;
        float* dst = (cr & 1) ? sdst : ssrc;
        #pragma unroll
        for (int m = 0; m < 2; ++m)
            #pragma unroll
            for (int qq = 0; qq < 4; ++qq)
                dst[((size_t)i * Nn + n) * Ee + j0 + m * 16 + 4 * g + qq] = sacc[m][qq];
    }
}

// ---------------------------------------------------------------------------
// K5a: scores -> softmax -> A-fragment store (split inline; no pack pass).
__global__ __launch_bounds__(256, 2) void score_kernel(
    const int*   __restrict__ adj,      // (N, E, E)
    const float* __restrict__ ssrc,     // (4, N, E)
    const float* __restrict__ sdst,     // (4, N, E)
    unsigned short* __restrict__ AH,    // (512 tiles, 16 ks, 2 m, 64 lane, 8)
    unsigned short* __restrict__ AL)
{
    int f  = blockIdx.x;
    int n  = (f & 7) * 4 + ((f >> 3) & 3);
    int rt = f >> 5;
    int tid = threadIdx.x;
    int row0 = rt * ROWS;

    __shared__ float coefT[Ee * 33];   // transposed coef [j][r], stride 33
    __shared__ float sdl[NT * Ee];
    __shared__ float ssl[NT * ROWS];

    for (int idx = tid; idx < NT * Ee; idx += 256) {
        int i = idx >> 9, j = idx & (Ee - 1);
        sdl[idx] = sdst[((size_t)i * Nn + n) * Ee + j];
    }
    for (int idx = tid; idx < NT * ROWS; idx += 256) {
        int i = idx >> 5, r = idx & 31;
        ssl[idx] = ssrc[((size_t)i * Nn + n) * Ee + row0 + r];
    }
    __syncthreads();

    const int* adjb = adj + ((size_t)n * Ee + row0) * Ee;
    for (int idx = tid; idx < ROWS * Ee; idx += 256) {
        int r = idx >> 9, j = idx & (Ee - 1);
        int t = adjb[idx];
        float v;
        if (t > 0) {
            float x = ssl[(t - 1) * ROWS + r] + sdl[(t - 1) * Ee + j];
            v = (x >= 0.f) ? x : SLOPE * x;
        } else {
            v = -1e30f;
        }
        coefT[j * 33 + r] = v;
    }
    __syncthreads();

    // softmax per row
    int wv = tid >> 6, lane = tid & 63;
    #pragma unroll
    for (int rr = 0; rr < 8; ++rr) {
        int r = wv * 8 + rr;
        float vals[8];
        float m = -3.0e38f;
        #pragma unroll
        for (int k = 0; k < 8; ++k) {
            vals[k] = coefT[(lane + 64 * k) * 33 + r];
            m = fmaxf(m, vals[k]);
        }
        #pragma unroll
        for (int off = 32; off; off >>= 1) m = fmaxf(m, __shfl_xor(m, off));
        float s = 0.f;
        #pragma unroll
        for (int k = 0; k < 8; ++k) {
            vals[k] = __expf(vals[k] - m);
            s += vals[k];
        }
        #pragma unroll
        for (int off = 32; off; off >>= 1) s += __shfl_xor(s, off);
        float inv = 1.f / s;
        #pragma unroll
        for (int k = 0; k < 8; ++k)
            coefT[(lane + 64 * k) * 33 + r] = vals[k] * inv;
    }
    __syncthreads();

    // A-fragment store: task t = ks*128 + m*64 + lane_; split inline.
    size_t tbase = ((size_t)(n * 16 + rt)) * 2048 * 8;
    for (int t = tid; t < 2048; t += 256) {
        int ks = t >> 7, rem = t & 127, m = rem >> 6, ln = rem & 63;
        int g2 = ln >> 4, cr2 = ln & 15;
        int k0 = ks * 32;
        bf16x8 hv, lv;
        #pragma unroll
        for (int jp = 0; jp < 8; ++jp) {
            float v = coefT[(k0 + 8 * g2 + jp) * 33 + m * 16 + cr2];
            unsigned short h = f2bf(v);
            hv[jp] = (short)h;
            lv[jp] = (short)f2bf(v - bf2f(h));
        }
        size_t o = tbase + (size_t)t * 8;
        *(bf16x8*)(AH + o) = hv;
        *(bf16x8*)(AL + o) = lv;
    }
}

// ---------------------------------------------------------------------------
// K5b: PV GEMM from pre-formatted fragments. No LDS, no barriers.
__global__ __launch_bounds__(256) void pv_kernel(
    const unsigned short* __restrict__ AH,
    const unsigned short* __restrict__ AL,
    const unsigned short* __restrict__ hmT_hi,  // (32, CPAD, 512)
    const unsigned short* __restrict__ hmT_lo,
    float* __restrict__ out)            // (N, E, 300)
{
    int f  = blockIdx.x;
    int n  = (f & 7) * 4 + ((f >> 3) & 3);
    int rt = f >> 5;
    int tid = threadIdx.x, wv = tid >> 6, lane = tid & 63;
    int g = lane >> 4, cr = lane & 15;
    int row0 = rt * ROWS;
    size_t tbase = ((size_t)(n * 16 + rt)) * 2048 * 8;

    f32x4 acc[5][2];
    #pragma unroll
    for (int a = 0; a < 5; ++a)
        #pragma unroll
        for (int m = 0; m < 2; ++m) acc[a][m] = (f32x4){0.f, 0.f, 0.f, 0.f};

    for (int ks = 0; ks < 16; ++ks) {
        bf16x8 ahi[2], alo[2];
        #pragma unroll
        for (int m = 0; m < 2; ++m) {
            size_t o = tbase + (size_t)((ks * 2 + m) * 64 + lane) * 8;
            ahi[m] = *(const bf16x8*)(AH + o);
            alo[m] = *(const bf16x8*)(AL + o);
        }
        int k0 = ks * 32;
        #pragma unroll
        for (int ntl = 0; ntl < 5; ++ntl) {
            int c = (wv + 4 * ntl) * 16 + cr;
            size_t off = ((size_t)(n * CPAD + c)) * Ee + k0 + 8 * g;
            bf16x8 bhi = *(const bf16x8*)(hmT_hi + off);
            bf16x8 blo = *(const bf16x8*)(hmT_lo + off);
            #pragma unroll
            for (int m = 0; m < 2; ++m) {
                acc[ntl][m] = __builtin_amdgcn_mfma_f32_16x16x32_bf16(ahi[m], bhi, acc[ntl][m], 0, 0, 0);
                acc[ntl][m] = __builtin_amdgcn_mfma_f32_16x16x32_bf16(ahi[m], blo, acc[ntl][m], 0, 0, 0);
                acc[ntl][m] = __builtin_amdgcn_mfma_f32_16x16x32_bf16(alo[m], bhi, acc[ntl][m], 0, 0, 0);
            }
        }
    }

    #pragma unroll
    for (int ntl = 0; ntl < 5; ++ntl) {
        int c = (wv + 4 * ntl) * 16 + cr;
        if (c < DOUT) {
            #pragma unroll
            for (int m = 0; m < 2; ++m) {
                #pragma unroll
                for (int q = 0; q < 4; ++q) {
                    int erow = row0 + m * 16 + 4 * g + q;
                    out[((size_t)n * Ee + erow) * DOUT + c] = acc[ntl][m][q];
                }
            }
        }
    }
}

// ---------------------------------------------------------------------------
// Fallback: fused scores->softmax->PV (used only if ws too small for split).
__global__ __launch_bounds__(256, 2) void attn_kernel(
    const int*   __restrict__ adj,
    const float* __restrict__ ssrc,
    const float* __restrict__ sdst,
    const unsigned short* __restrict__ hmT_hi,
    const unsigned short* __restrict__ hmT_lo,
    float* __restrict__ out)
{
    int f  = blockIdx.x;
    int n  = (f & 7) * 4 + ((f >> 3) & 3);
    int rt = f >> 5;
    int tid = threadIdx.x;
    int row0 = rt * ROWS;

    __shared__ unsigned coefT[Ee * 33];
    __shared__ float sdl[NT * Ee];
    __shared__ float ssl[NT * ROWS];

    for (int idx = tid; idx < NT * Ee; idx += 256) {
        int i = idx >> 9, j = idx & (Ee - 1);
        sdl[idx] = sdst[((size_t)i * Nn + n) * Ee + j];
    }
    for (int idx = tid; idx < NT * ROWS; idx += 256) {
        int i = idx >> 5, r = idx & 31;
        ssl[idx] = ssrc[((size_t)i * Nn + n) * Ee + row0 + r];
    }
    __syncthreads();

    const int* adjb = adj + ((size_t)n * Ee + row0) * Ee;
    for (int idx = tid; idx < ROWS * Ee; idx += 256) {
        int r = idx >> 9, j = idx & (Ee - 1);
        int t = adjb[idx];
        float v;
        if (t > 0) {
            float x = ssl[(t - 1) * ROWS + r] + sdl[(t - 1) * Ee + j];
            v = (x >= 0.f) ? x : SLOPE * x;
        } else {
            v = -1e30f;
        }
        coefT[j * 33 + r] = __float_as_uint(v);
    }
    __syncthreads();

    int wv = tid >> 6, lane = tid & 63;
    #pragma unroll
    for (int rr = 0; rr < 8; ++rr) {
        int r = wv * 8 + rr;
        float vals[8];
        float m = -3.0e38f;
        #pragma unroll
        for (int k = 0; k < 8; ++k) {
            vals[k] = __uint_as_float(coefT[(lane + 64 * k) * 33 + r]);
            m = fmaxf(m, vals[k]);
        }
        #pragma unroll
        for (int off = 32; off; off >>= 1) m = fmaxf(m, __shfl_xor(m, off));
        float s = 0.f;
        #pragma unroll
        for (int k = 0; k < 8; ++k) {
            vals[k] = __expf(vals[k] - m);
            s += vals[k];
        }
        #pragma unroll
        for (int off = 32; off; off >>= 1) s += __shfl_xor(s, off);
        float inv = 1.f / s;
        #pragma unroll
        for (int k = 0; k < 8; ++k)
            coefT[(lane + 64 * k) * 33 + r] = __float_as_uint(vals[k] * inv);
    }
    __syncthreads();

    for (int idx = tid; idx < Ee * ROWS; idx += 256) {
        int j = idx >> 5, r = idx & 31;
        float v = __uint_as_float(coefT[j * 33 + r]);
        unsigned short hi = f2bf(v);
        unsigned short lo = f2bf(v - bf2f(hi));
        coefT[j * 33 + r] = ((unsigned)hi << 16) | (unsigned)lo;
    }
    __syncthreads();

    int g = lane >> 4;
    int cr = lane & 15;
    f32x4 acc[5][2];
    #pragma unroll
    for (int a = 0; a < 5; ++a)
        #pragma unroll
        for (int m = 0; m < 2; ++m) acc[a][m] = (f32x4){0.f, 0.f, 0.f, 0.f};

    for (int ks = 0; ks < 16; ++ks) {
        int k0 = ks * 32;
        bf16x8 ahi[2], alo[2];
        #pragma unroll
        for (int m = 0; m < 2; ++m) {
            #pragma unroll
            for (int j = 0; j < 8; ++j) {
                unsigned v = coefT[(k0 + 8 * g + j) * 33 + m * 16 + cr];
                ahi[m][j] = (short)(v >> 16);
                alo[m][j] = (short)(v & 0xffffu);
            }
        }
        #pragma unroll
        for (int ntl = 0; ntl < 5; ++ntl) {
            int c = (wv + 4 * ntl) * 16 + cr;
            size_t off = ((size_t)(n * CPAD + c)) * Ee + k0 + 8 * g;
            bf16x8 bhi = *(const bf16x8*)(hmT_hi + off);
            bf16x8 blo = *(const bf16x8*)(hmT_lo + off);
            #pragma unroll
            for (int m = 0; m < 2; ++m) {
                acc[ntl][m] = __builtin_amdgcn_mfma_f32_16x16x32_bf16(ahi[m], bhi, acc[ntl][m], 0, 0, 0);
                acc[ntl][m] = __builtin_amdgcn_mfma_f32_16x16x32_bf16(ahi[m], blo, acc[ntl][m], 0, 0, 0);
                acc[ntl][m] = __builtin_amdgcn_mfma_f32_16x16x32_bf16(alo[m], bhi, acc[ntl][m], 0, 0, 0);
            }
        }
    }

    #pragma unroll
    for (int ntl = 0; ntl < 5; ++ntl) {
        int c = (wv + 4 * ntl) * 16 + cr;
        if (c < DOUT) {
            #pragma unroll
            for (int m = 0; m < 2; ++m) {
                #pragma unroll
                for (int q = 0; q < 4; ++q) {
                    int erow = row0 + m * 16 + 4 * g + q;
                    out[((size_t)n * Ee + erow) * DOUT + c] = acc[ntl][m][q];
                }
            }
        }
    }
}

// ---------------------------------------------------------------------------
extern "C" void kernel_launch(void* const* d_in, const int* in_sizes, int n_in,
                              void* d_out, int out_size, void* d_ws, size_t ws_size,
                              hipStream_t stream) {
    const float* input_state = (const float*)d_in[0];
    const int*   adj         = (const int*)  d_in[1];
    const float* node_mask   = (const float*)d_in[2];
    const float* query_vec   = (const float*)d_in[3];
    const float* W_type      = (const float*)d_in[4];
    const float* a_type      = (const float*)d_in[5];
    const float* qattn_W1    = (const float*)d_in[6];
    const float* qattn_W2    = (const float*)d_in[7];
    float* out = (float*)d_out;

    // workspace layout
    float* ws   = (float*)d_ws;
    float* g    = ws;                 // 76800 f
    float* t1   = g    + 76800;       // 76800 f
    float* ssrc = t1   + 76800;       // 65536 f
    float* sdst = ssrc + 65536;       // 65536 f
    unsigned short* W3T_hi = (unsigned short*)(sdst + 65536);   // 102400 u16
    unsigned short* W3T_lo = W3T_hi + 320 * 320;                // 102400 u16
    unsigned short* UTh    = W3T_lo + 320 * 320;                // 163840 u16
    unsigned short* UTl    = UTh + 32 * 16 * 320;               // 163840 u16
    unsigned short* hmT_hi = UTl + 32 * 16 * 320;               // 5242880 u16
    unsigned short* hmT_lo = hmT_hi + (size_t)Nn * CPAD * Ee;   // 5242880 u16
    unsigned short* AH     = hmT_lo + (size_t)Nn * CPAD * Ee;   // 8388608 u16
    unsigned short* AL     = AH + (size_t)512 * 2048 * 8;       // 8388608 u16

    size_t need_split = (size_t)((char*)(AL + (size_t)512 * 2048 * 8) - (char*)d_ws);
    bool use_split = ws_size >= need_split;

    hipLaunchKernelGGL(prep_kernel, dim3(640), dim3(256), 0, stream,
                       W_type + 3 * DIN * DOUT, W3T_hi, W3T_lo, UTh, UTl);
    hipLaunchKernelGGL(gates1_kernel, dim3(75, NT), dim3(256), 0, stream,
                       query_vec, qattn_W1, t1);
    hipLaunchKernelGGL(gates2_kernel, dim3(75, NT), dim3(256), 0, stream,
                       t1, qattn_W2, g);
    hipLaunchKernelGGL(uvec_kernel, dim3(NT, Nn, 8), dim3(64), 0, stream,
                       W_type, a_type, g, UTh, UTl);
    hipLaunchKernelGGL(hm_mfma_kernel, dim3((Nn * Ee) / 32), dim3(256), 0, stream,
                       input_state, node_mask, W3T_hi, W3T_lo, UTh, UTl,
                       hmT_hi, hmT_lo, ssrc, sdst);
    if (use_split) {
        hipLaunchKernelGGL(score_kernel, dim3(512), dim3(256), 0, stream,
                           adj, ssrc, sdst, AH, AL);
        hipLaunchKernelGGL(pv_kernel, dim3(512), dim3(256), 0, stream,
                           AH, AL, hmT_hi, hmT_lo, out);
    } else {
        hipLaunchKernelGGL(attn_kernel, dim3(512), dim3(256), 0, stream,
                           adj, ssrc, sdst, hmT_hi, hmT_lo, out);
    }
}

// Round 8
// 174.324 us; speedup vs baseline: 1.6936x; 1.3185x over previous
//
#include <hip/hip_runtime.h>
#include <hip/hip_bf16.h>

// Problem constants
#define Nn   32
#define Ee   512
#define DIN  300
#define DOUT 300
#define NT   4
#define QD   300
#define SLOPE 0.2f
#define ROWS 32   // rows per tile in score/pv kernels
#define CPAD 320  // padded d-dim for hmT (20 MFMA n-tiles of 16)

typedef __attribute__((ext_vector_type(8))) short bf16x8;
typedef __attribute__((ext_vector_type(4))) float f32x4;
typedef __attribute__((ext_vector_type(4))) unsigned short u16x4;

__device__ inline unsigned short f2bf(float x) {
    __hip_bfloat16 h = __float2bfloat16(x);   // RNE
    return *reinterpret_cast<unsigned short*>(&h);
}
__device__ inline float bf2f(unsigned short u) {
    __hip_bfloat16 h = *reinterpret_cast<__hip_bfloat16*>(&u);
    return __bfloat162float(h);
}

// ---------------------------------------------------------------------------
// K0: prep. W3T split planes [c=320][k=320] (W3T[c][k] = W3[k][c], pad 0),
// zero UT planes [32][16][320], zero GT planes [4][64][320].
__global__ __launch_bounds__(256) void prep_kernel(
    const float* __restrict__ W3,          // (300, 300)  row k, col d
    unsigned short* __restrict__ W3T_hi,   // (320, 320)
    unsigned short* __restrict__ W3T_lo,
    unsigned short* __restrict__ UTh,      // (32, 16, 320)
    unsigned short* __restrict__ UTl,
    unsigned short* __restrict__ GTh,      // (4, 64, 320)
    unsigned short* __restrict__ GTl)
{
    int idx = blockIdx.x * 256 + threadIdx.x;   // grid 640 -> 163840 threads
    if (idx < 320 * 320) {
        int c = idx / 320, k = idx - c * 320;
        float v = (c < DOUT && k < DIN) ? W3[(size_t)k * DOUT + c] : 0.f;
        unsigned short h = f2bf(v);
        W3T_hi[idx] = h;
        W3T_lo[idx] = f2bf(v - bf2f(h));
    }
    if (idx < 32 * 16 * 320) { UTh[idx] = 0; UTl[idx] = 0; }
    if (idx < 4 * 64 * 320)  { GTh[idx] = 0; GTl[idx] = 0; }
}

// ---------------------------------------------------------------------------
// K1a: gates1 partial. t1p[z][i][n][j] = sum_{k in slab z} q[n][k]*W1[i][k][j]
// grid (75, NT, 4), block 256.
__global__ __launch_bounds__(256) void gates1_part_kernel(
    const float* __restrict__ q,    // (32, 300)
    const float* __restrict__ W1,   // (4, 300, 600)
    float* __restrict__ t1p)        // (4, 4, 32, 600)
{
    int i = blockIdx.y, z = blockIdx.z;
    int idx = blockIdx.x * 256 + threadIdx.x;   // 0..19199
    int n = idx / 600, j = idx - n * 600;
    const float* W1i = W1 + (size_t)i * QD * 600;
    const float* qn = q + n * QD;
    int k0 = z * 75;
    float a0 = 0.f;
    #pragma unroll 5
    for (int k = k0; k < k0 + 75; ++k)
        a0 += qn[k] * W1i[(size_t)k * 600 + j];
    t1p[((size_t)(z * NT + i) * Nn + n) * 600 + j] = a0;
}

// K1a-fin: t1 = relu(sum_z t1p). grid (75, NT).
__global__ __launch_bounds__(256) void gates1_fin_kernel(
    const float* __restrict__ t1p, float* __restrict__ t1)
{
    int i = blockIdx.y;
    int idx = blockIdx.x * 256 + threadIdx.x;
    size_t o = ((size_t)i * Nn) * 600 + idx;
    float s = t1p[o] + t1p[o + 76800] + t1p[o + 2 * 76800] + t1p[o + 3 * 76800];
    t1[o] = fmaxf(s, 0.f);
}

// ---------------------------------------------------------------------------
// K1b: gates2 partial. K=600, 4 slabs of 150.
__global__ __launch_bounds__(256) void gates2_part_kernel(
    const float* __restrict__ t1,   // (4, 32, 600)
    const float* __restrict__ W2,   // (4, 600, 600)
    float* __restrict__ gp)         // (4, 4, 32, 600)
{
    int i = blockIdx.y, z = blockIdx.z;
    int idx = blockIdx.x * 256 + threadIdx.x;
    int n = idx / 600, j = idx - n * 600;
    const float* W2i = W2 + (size_t)i * 600 * 600;
    const float* tn = t1 + ((size_t)i * Nn + n) * 600;
    int k0 = z * 150;
    float a0 = 0.f, a1 = 0.f;
    #pragma unroll 5
    for (int k = k0; k < k0 + 150; k += 2) {
        a0 += tn[k]     * W2i[(size_t)k * 600 + j];
        a1 += tn[k + 1] * W2i[(size_t)(k + 1) * 600 + j];
    }
    gp[((size_t)(z * NT + i) * Nn + n) * 600 + j] = a0 + a1;
}

// K1b-fin: gate = sigmoid(sum_z gp) * a  -> GT split planes [i][2n+s][d].
// grid (75, NT).
__global__ __launch_bounds__(256) void gates2_fin_kernel(
    const float* __restrict__ gp,
    const float* __restrict__ a,    // (4, 600)
    unsigned short* __restrict__ GTh,   // (4, 64, 320)
    unsigned short* __restrict__ GTl)
{
    int i = blockIdx.y;
    int idx = blockIdx.x * 256 + threadIdx.x;
    int n = idx / 600, j = idx - n * 600;
    size_t o = ((size_t)i * Nn + n) * 600 + j;
    float s = gp[o] + gp[o + 76800] + gp[o + 2 * 76800] + gp[o + 3 * 76800];
    float w = (1.f / (1.f + __expf(-s))) * a[(size_t)i * 600 + j];
    int s2 = (j >= DOUT) ? 1 : 0;
    int d = j - s2 * DOUT;
    int c = 2 * n + s2;
    size_t go = ((size_t)i * 64 + c) * 320 + d;
    unsigned short h = f2bf(w);
    GTh[go] = h;
    GTl[go] = f2bf(w - bf2f(h));
}

// ---------------------------------------------------------------------------
// K2: uvec via MFMA. Per type i: U = W[i](300k x 300d) @ GT[i]^T(300d x 64c).
// grid (5, NT), block 256 (4 waves). Wave wv: m-tile rows [mc*64+wv*16, +16).
// Output straight into UT planes (row n*16 + 2i+s, k-contiguous).
__global__ __launch_bounds__(256) void uvec_mfma_kernel(
    const float* __restrict__ W,            // (4, 300, 300)
    const unsigned short* __restrict__ GTh, // (4, 64, 320)
    const unsigned short* __restrict__ GTl,
    unsigned short* __restrict__ UTh,       // (32, 16, 320)
    unsigned short* __restrict__ UTl)
{
    int mc = blockIdx.x, i = blockIdx.y;
    int tid = threadIdx.x, wv = tid >> 6, lane = tid & 63;
    int g = lane >> 4, cr = lane & 15;
    int m0 = mc * 64 + wv * 16;
    int arow = m0 + cr;
    const float* wr = W + (size_t)i * DIN * DOUT
                        + (size_t)(arow < DIN ? arow : 0) * DOUT;

    f32x4 acc[4];
    #pragma unroll
    for (int nt = 0; nt < 4; ++nt) acc[nt] = (f32x4){0.f, 0.f, 0.f, 0.f};

    for (int ks = 0; ks < 10; ++ks) {
        int k0 = ks * 32 + 8 * g;
        float x8[8];
        if (ks < 9) {
            f32x4 v0 = *(const f32x4*)(wr + k0);
            f32x4 v1 = *(const f32x4*)(wr + k0 + 4);
            #pragma unroll
            for (int j = 0; j < 4; ++j) { x8[j] = v0[j]; x8[4 + j] = v1[j]; }
        } else {
            #pragma unroll
            for (int j = 0; j < 8; ++j) {
                int d = k0 + j;
                x8[j] = (d < DOUT) ? wr[d] : 0.f;
            }
        }
        bf16x8 ahi, alo;
        #pragma unroll
        for (int j = 0; j < 8; ++j) {
            unsigned short h = f2bf(x8[j]);
            ahi[j] = (short)h;
            alo[j] = (short)f2bf(x8[j] - bf2f(h));
        }
        #pragma unroll
        for (int nt = 0; nt < 4; ++nt) {
            size_t bo = ((size_t)i * 64 + nt * 16 + cr) * 320 + k0;
            bf16x8 bh = *(const bf16x8*)(GTh + bo);
            bf16x8 bl = *(const bf16x8*)(GTl + bo);
            acc[nt] = __builtin_amdgcn_mfma_f32_16x16x32_bf16(ahi, bh, acc[nt], 0, 0, 0);
            acc[nt] = __builtin_amdgcn_mfma_f32_16x16x32_bf16(ahi, bl, acc[nt], 0, 0, 0);
            acc[nt] = __builtin_amdgcn_mfma_f32_16x16x32_bf16(alo, bh, acc[nt], 0, 0, 0);
        }
    }

    int krow = m0 + 4 * g;   // 4-aligned; 300%4==0 so group fully in or out
    if (krow < DIN) {
        #pragma unroll
        for (int nt = 0; nt < 4; ++nt) {
            int c = nt * 16 + cr;
            int n = c >> 1, s = c & 1;
            size_t base = ((size_t)n * 16 + 2 * i + s) * 320 + krow;
            u16x4 h4, l4;
            #pragma unroll
            for (int q = 0; q < 4; ++q) {
                float v = acc[nt][q];
                unsigned short h = f2bf(v);
                h4[q] = h;
                l4[q] = f2bf(v - bf2f(h));
            }
            *(u16x4*)(UTh + base) = h4;
            *(u16x4*)(UTl + base) = l4;
        }
    }
}

// ---------------------------------------------------------------------------
// K4: MFMA hm GEMM + fused sdot (unchanged from round 6).
__global__ __launch_bounds__(256) void hm_mfma_kernel(
    const float* __restrict__ X,               // (16384, 300)
    const float* __restrict__ mask,            // (16384)
    const unsigned short* __restrict__ W3T_hi, // (320, 320)
    const unsigned short* __restrict__ W3T_lo,
    const unsigned short* __restrict__ UTh,    // (32, 16, 320)
    const unsigned short* __restrict__ UTl,
    unsigned short* __restrict__ hmT_hi,       // (32, CPAD, 512)
    unsigned short* __restrict__ hmT_lo,
    float* __restrict__ ssrc,                  // (4, 32, 512)
    float* __restrict__ sdst)
{
    int tid = threadIdx.x, wv = tid >> 6, lane = tid & 63;
    int g = lane >> 4, cr = lane & 15;
    size_t row0 = (size_t)blockIdx.x * 32;
    int n = (int)(row0 >> 9), j0 = (int)(row0 & 511);

    __shared__ float maskL[32];
    if (tid < 32) maskL[tid] = mask[row0 + tid];
    __syncthreads();

    f32x4 acc[5][2];
    f32x4 sacc[2];
    #pragma unroll
    for (int a = 0; a < 5; ++a)
        #pragma unroll
        for (int m = 0; m < 2; ++m) acc[a][m] = (f32x4){0.f, 0.f, 0.f, 0.f};
    sacc[0] = (f32x4){0.f, 0.f, 0.f, 0.f};
    sacc[1] = (f32x4){0.f, 0.f, 0.f, 0.f};

    const float* xr0 = X + (row0 + cr) * DIN;        // m=0 row
    const float* xr1 = X + (row0 + 16 + cr) * DIN;   // m=1 row

    for (int ks = 0; ks < 10; ++ks) {
        int k0 = ks * 32 + 8 * g;     // per-lane k base
        bf16x8 ahi[2], alo[2];
        #pragma unroll
        for (int m = 0; m < 2; ++m) {
            const float* xr = m ? xr1 : xr0;
            float x8[8];
            if (ks < 9) {
                f32x4 v0 = *(const f32x4*)(xr + k0);
                f32x4 v1 = *(const f32x4*)(xr + k0 + 4);
                #pragma unroll
                for (int j = 0; j < 4; ++j) { x8[j] = v0[j]; x8[4 + j] = v1[j]; }
            } else {
                #pragma unroll
                for (int j = 0; j < 8; ++j) {
                    int k = k0 + j;
                    x8[j] = (k < DIN) ? xr[k] : 0.f;
                }
            }
            #pragma unroll
            for (int j = 0; j < 8; ++j) {
                unsigned short h = f2bf(x8[j]);
                ahi[m][j] = (short)h;
                alo[m][j] = (short)f2bf(x8[j] - bf2f(h));
            }
        }
        #pragma unroll
        for (int ntl = 0; ntl < 5; ++ntl) {
            int c = (wv + 4 * ntl) * 16 + cr;
            bf16x8 bh = *(const bf16x8*)(W3T_hi + (size_t)c * 320 + k0);
            bf16x8 bl = *(const bf16x8*)(W3T_lo + (size_t)c * 320 + k0);
            #pragma unroll
            for (int m = 0; m < 2; ++m) {
                acc[ntl][m] = __builtin_amdgcn_mfma_f32_16x16x32_bf16(ahi[m], bh, acc[ntl][m], 0, 0, 0);
                acc[ntl][m] = __builtin_amdgcn_mfma_f32_16x16x32_bf16(ahi[m], bl, acc[ntl][m], 0, 0, 0);
                acc[ntl][m] = __builtin_amdgcn_mfma_f32_16x16x32_bf16(alo[m], bh, acc[ntl][m], 0, 0, 0);
            }
        }
        if (wv == 0) {
            bf16x8 uh = *(const bf16x8*)(UTh + ((size_t)n * 16 + cr) * 320 + k0);
            bf16x8 ul = *(const bf16x8*)(UTl + ((size_t)n * 16 + cr) * 320 + k0);
            #pragma unroll
            for (int m = 0; m < 2; ++m) {
                sacc[m] = __builtin_amdgcn_mfma_f32_16x16x32_bf16(ahi[m], uh, sacc[m], 0, 0, 0);
                sacc[m] = __builtin_amdgcn_mfma_f32_16x16x32_bf16(ahi[m], ul, sacc[m], 0, 0, 0);
                sacc[m] = __builtin_amdgcn_mfma_f32_16x16x32_bf16(alo[m], uh, sacc[m], 0, 0, 0);
            }
        }
    }

    // hm epilogue: mask, split, transposed store (q contiguous in j -> 8B)
    #pragma unroll
    for (int ntl = 0; ntl < 5; ++ntl) {
        int c = (wv + 4 * ntl) * 16 + cr;
        #pragma unroll
        for (int m = 0; m < 2; ++m) {
            u16x4 h4, l4;
            #pragma unroll
            for (int qq = 0; qq < 4; ++qq) {
                float v = acc[ntl][m][qq] * maskL[m * 16 + 4 * g + qq];
                unsigned short h = f2bf(v);
                h4[qq] = h;
                l4[qq] = f2bf(v - bf2f(h));
            }
            size_t off = ((size_t)(n * CPAD + c)) * Ee + j0 + m * 16 + 4 * g;
            *(u16x4*)(hmT_hi + off) = h4;
            *(u16x4*)(hmT_lo + off) = l4;
        }
    }

    // sdot epilogue: D[row][c], c=2i -> ssrc, c=2i+1 -> sdst
    if (wv == 0 && cr < 8) {
        int i = cr >> 1;
        float* dst = (cr & 1) ? sdst : ssrc;
        #pragma unroll
        for (int m = 0; m < 2; ++m)
            #pragma unroll
            for (int qq = 0; qq < 4; ++qq)
                dst[((size_t)i * Nn + n) * Ee + j0 + m * 16 + 4 * g + qq] = sacc[m][qq];
    }
}

// ---------------------------------------------------------------------------
// K5a: scores -> softmax -> A-fragment store (split inline; no pack pass).
__global__ __launch_bounds__(256, 2) void score_kernel(
    const int*   __restrict__ adj,      // (N, E, E)
    const float* __restrict__ ssrc,     // (4, N, E)
    const float* __restrict__ sdst,     // (4, N, E)
    unsigned short* __restrict__ AH,    // (512 tiles, 16 ks, 2 m, 64 lane, 8)
    unsigned short* __restrict__ AL)
{
    int f  = blockIdx.x;
    int n  = (f & 7) * 4 + ((f >> 3) & 3);
    int rt = f >> 5;
    int tid = threadIdx.x;
    int row0 = rt * ROWS;

    __shared__ float coefT[Ee * 33];   // transposed coef [j][r], stride 33
    __shared__ float sdl[NT * Ee];
    __shared__ float ssl[NT * ROWS];

    for (int idx = tid; idx < NT * Ee; idx += 256) {
        int i = idx >> 9, j = idx & (Ee - 1);
        sdl[idx] = sdst[((size_t)i * Nn + n) * Ee + j];
    }
    for (int idx = tid; idx < NT * ROWS; idx += 256) {
        int i = idx >> 5, r = idx & 31;
        ssl[idx] = ssrc[((size_t)i * Nn + n) * Ee + row0 + r];
    }
    __syncthreads();

    const int* adjb = adj + ((size_t)n * Ee + row0) * Ee;
    for (int idx = tid; idx < ROWS * Ee; idx += 256) {
        int r = idx >> 9, j = idx & (Ee - 1);
        int t = adjb[idx];
        float v;
        if (t > 0) {
            float x = ssl[(t - 1) * ROWS + r] + sdl[(t - 1) * Ee + j];
            v = (x >= 0.f) ? x : SLOPE * x;
        } else {
            v = -1e30f;
        }
        coefT[j * 33 + r] = v;
    }
    __syncthreads();

    // softmax per row
    int wv = tid >> 6, lane = tid & 63;
    #pragma unroll
    for (int rr = 0; rr < 8; ++rr) {
        int r = wv * 8 + rr;
        float vals[8];
        float m = -3.0e38f;
        #pragma unroll
        for (int k = 0; k < 8; ++k) {
            vals[k] = coefT[(lane + 64 * k) * 33 + r];
            m = fmaxf(m, vals[k]);
        }
        #pragma unroll
        for (int off = 32; off; off >>= 1) m = fmaxf(m, __shfl_xor(m, off));
        float s = 0.f;
        #pragma unroll
        for (int k = 0; k < 8; ++k) {
            vals[k] = __expf(vals[k] - m);
            s += vals[k];
        }
        #pragma unroll
        for (int off = 32; off; off >>= 1) s += __shfl_xor(s, off);
        float inv = 1.f / s;
        #pragma unroll
        for (int k = 0; k < 8; ++k)
            coefT[(lane + 64 * k) * 33 + r] = vals[k] * inv;
    }
    __syncthreads();

    // A-fragment store: task t = ks*128 + m*64 + lane_; split inline.
    size_t tbase = ((size_t)(n * 16 + rt)) * 2048 * 8;
    for (int t = tid; t < 2048; t += 256) {
        int ks = t >> 7, rem = t & 127, m = rem >> 6, ln = rem & 63;
        int g2 = ln >> 4, cr2 = ln & 15;
        int k0 = ks * 32;
        bf16x8 hv, lv;
        #pragma unroll
        for (int jp = 0; jp < 8; ++jp) {
            float v = coefT[(k0 + 8 * g2 + jp) * 33 + m * 16 + cr2];
            unsigned short h = f2bf(v);
            hv[jp] = (short)h;
            lv[jp] = (short)f2bf(v - bf2f(h));
        }
        size_t o = tbase + (size_t)t * 8;
        *(bf16x8*)(AH + o) = hv;
        *(bf16x8*)(AL + o) = lv;
    }
}

// ---------------------------------------------------------------------------
// K5b: PV GEMM from pre-formatted fragments. No LDS, no barriers.
__global__ __launch_bounds__(256) void pv_kernel(
    const unsigned short* __restrict__ AH,
    const unsigned short* __restrict__ AL,
    const unsigned short* __restrict__ hmT_hi,  // (32, CPAD, 512)
    const unsigned short* __restrict__ hmT_lo,
    float* __restrict__ out)            // (N, E, 300)
{
    int f  = blockIdx.x;
    int n  = (f & 7) * 4 + ((f >> 3) & 3);
    int rt = f >> 5;
    int tid = threadIdx.x, wv = tid >> 6, lane = tid & 63;
    int g = lane >> 4, cr = lane & 15;
    int row0 = rt * ROWS;
    size_t tbase = ((size_t)(n * 16 + rt)) * 2048 * 8;

    f32x4 acc[5][2];
    #pragma unroll
    for (int a = 0; a < 5; ++a)
        #pragma unroll
        for (int m = 0; m < 2; ++m) acc[a][m] = (f32x4){0.f, 0.f, 0.f, 0.f};

    for (int ks = 0; ks < 16; ++ks) {
        bf16x8 ahi[2], alo[2];
        #pragma unroll
        for (int m = 0; m < 2; ++m) {
            size_t o = tbase + (size_t)((ks * 2 + m) * 64 + lane) * 8;
            ahi[m] = *(const bf16x8*)(AH + o);
            alo[m] = *(const bf16x8*)(AL + o);
        }
        int k0 = ks * 32;
        #pragma unroll
        for (int ntl = 0; ntl < 5; ++ntl) {
            int c = (wv + 4 * ntl) * 16 + cr;
            size_t off = ((size_t)(n * CPAD + c)) * Ee + k0 + 8 * g;
            bf16x8 bhi = *(const bf16x8*)(hmT_hi + off);
            bf16x8 blo = *(const bf16x8*)(hmT_lo + off);
            #pragma unroll
            for (int m = 0; m < 2; ++m) {
                acc[ntl][m] = __builtin_amdgcn_mfma_f32_16x16x32_bf16(ahi[m], bhi, acc[ntl][m], 0, 0, 0);
                acc[ntl][m] = __builtin_amdgcn_mfma_f32_16x16x32_bf16(ahi[m], blo, acc[ntl][m], 0, 0, 0);
                acc[ntl][m] = __builtin_amdgcn_mfma_f32_16x16x32_bf16(alo[m], bhi, acc[ntl][m], 0, 0, 0);
            }
        }
    }

    #pragma unroll
    for (int ntl = 0; ntl < 5; ++ntl) {
        int c = (wv + 4 * ntl) * 16 + cr;
        if (c < DOUT) {
            #pragma unroll
            for (int m = 0; m < 2; ++m) {
                #pragma unroll
                for (int q = 0; q < 4; ++q) {
                    int erow = row0 + m * 16 + 4 * g + q;
                    out[((size_t)n * Ee + erow) * DOUT + c] = acc[ntl][m][q];
                }
            }
        }
    }
}

// ---------------------------------------------------------------------------
// Fallback-path kernels (only if ws too small for split; never expected).
__global__ __launch_bounds__(256) void gates1_kernel(
    const float* __restrict__ q, const float* __restrict__ W1,
    float* __restrict__ t1)
{
    int i = blockIdx.y;
    int idx = blockIdx.x * 256 + threadIdx.x;
    int n = idx / 600, j = idx - n * 600;
    const float* W1i = W1 + (size_t)i * QD * 600;
    const float* qn = q + n * QD;
    float a0 = 0.f, a1 = 0.f;
    #pragma unroll 5
    for (int k = 0; k < QD; k += 2) {
        a0 += qn[k]     * W1i[(size_t)k * 600 + j];
        a1 += qn[k + 1] * W1i[(size_t)(k + 1) * 600 + j];
    }
    t1[((size_t)i * Nn + n) * 600 + j] = fmaxf(a0 + a1, 0.f);
}

__global__ __launch_bounds__(256) void gates2_kernel(
    const float* __restrict__ t1, const float* __restrict__ W2,
    float* __restrict__ g)
{
    int i = blockIdx.y;
    int idx = blockIdx.x * 256 + threadIdx.x;
    int n = idx / 600, j = idx - n * 600;
    const float* W2i = W2 + (size_t)i * 600 * 600;
    const float* tn = t1 + ((size_t)i * Nn + n) * 600;
    float a0 = 0.f, a1 = 0.f;
    #pragma unroll 5
    for (int k = 0; k < 600; k += 2) {
        a0 += tn[k]     * W2i[(size_t)k * 600 + j];
        a1 += tn[k + 1] * W2i[(size_t)(k + 1) * 600 + j];
    }
    g[((size_t)i * Nn + n) * 600 + j] = 1.f / (1.f + __expf(-(a0 + a1)));
}

__global__ __launch_bounds__(64) void uvec_kernel(
    const float* __restrict__ W, const float* __restrict__ a,
    const float* __restrict__ g,
    unsigned short* __restrict__ UTh, unsigned short* __restrict__ UTl)
{
    int i = blockIdx.x, n = blockIdx.y, kt = blockIdx.z;
    int lane = threadIdx.x;
    __shared__ float w1[DOUT], w2[DOUT];

    const float* gi = g + ((size_t)i * Nn + n) * 600;
    const float* ai = a + (size_t)i * 600;
    for (int d = lane; d < DOUT; d += 64) {
        w1[d] = gi[d] * ai[d];
        w2[d] = gi[DOUT + d] * ai[DOUT + d];
    }
    __syncthreads();

    int k0 = kt * 38;
    int k1 = k0 + 38 < DIN ? k0 + 38 : DIN;
    const float* Wi = W + (size_t)i * DIN * DOUT;
    for (int k = k0; k < k1; ++k) {
        const float* Wk = Wi + (size_t)k * DOUT;
        float s1 = 0.f, s2 = 0.f;
        #pragma unroll
        for (int c = 0; c < 5; ++c) {
            int d = lane + 64 * c;
            if (d < DOUT) { float w = Wk[d]; s1 += w * w1[d]; s2 += w * w2[d]; }
        }
        #pragma unroll
        for (int off = 32; off; off >>= 1) {
            s1 += __shfl_xor(s1, off);
            s2 += __shfl_xor(s2, off);
        }
        if (lane == 0) {
            unsigned short h1 = f2bf(s1), l1 = f2bf(s1 - bf2f(h1));
            unsigned short h2 = f2bf(s2), l2 = f2bf(s2 - bf2f(h2));
            size_t b = ((size_t)n * 16 + 2 * i) * 320 + k;
            UTh[b] = h1;       UTl[b] = l1;
            UTh[b + 320] = h2; UTl[b + 320] = l2;
        }
    }
}

__global__ __launch_bounds__(256, 2) void attn_kernel(
    const int*   __restrict__ adj,
    const float* __restrict__ ssrc,
    const float* __restrict__ sdst,
    const unsigned short* __restrict__ hmT_hi,
    const unsigned short* __restrict__ hmT_lo,
    float* __restrict__ out)
{
    int f  = blockIdx.x;
    int n  = (f & 7) * 4 + ((f >> 3) & 3);
    int rt = f >> 5;
    int tid = threadIdx.x;
    int row0 = rt * ROWS;

    __shared__ unsigned coefT[Ee * 33];
    __shared__ float sdl[NT * Ee];
    __shared__ float ssl[NT * ROWS];

    for (int idx = tid; idx < NT * Ee; idx += 256) {
        int i = idx >> 9, j = idx & (Ee - 1);
        sdl[idx] = sdst[((size_t)i * Nn + n) * Ee + j];
    }
    for (int idx = tid; idx < NT * ROWS; idx += 256) {
        int i = idx >> 5, r = idx & 31;
        ssl[idx] = ssrc[((size_t)i * Nn + n) * Ee + row0 + r];
    }
    __syncthreads();

    const int* adjb = adj + ((size_t)n * Ee + row0) * Ee;
    for (int idx = tid; idx < ROWS * Ee; idx += 256) {
        int r = idx >> 9, j = idx & (Ee - 1);
        int t = adjb[idx];
        float v;
        if (t > 0) {
            float x = ssl[(t - 1) * ROWS + r] + sdl[(t - 1) * Ee + j];
            v = (x >= 0.f) ? x : SLOPE * x;
        } else {
            v = -1e30f;
        }
        coefT[j * 33 + r] = __float_as_uint(v);
    }
    __syncthreads();

    int wv = tid >> 6, lane = tid & 63;
    #pragma unroll
    for (int rr = 0; rr < 8; ++rr) {
        int r = wv * 8 + rr;
        float vals[8];
        float m = -3.0e38f;
        #pragma unroll
        for (int k = 0; k < 8; ++k) {
            vals[k] = __uint_as_float(coefT[(lane + 64 * k) * 33 + r]);
            m = fmaxf(m, vals[k]);
        }
        #pragma unroll
        for (int off = 32; off; off >>= 1) m = fmaxf(m, __shfl_xor(m, off));
        float s = 0.f;
        #pragma unroll
        for (int k = 0; k < 8; ++k) {
            vals[k] = __expf(vals[k] - m);
            s += vals[k];
        }
        #pragma unroll
        for (int off = 32; off; off >>= 1) s += __shfl_xor(s, off);
        float inv = 1.f / s;
        #pragma unroll
        for (int k = 0; k < 8; ++k)
            coefT[(lane + 64 * k) * 33 + r] = __float_as_uint(vals[k] * inv);
    }
    __syncthreads();

    for (int idx = tid; idx < Ee * ROWS; idx += 256) {
        int j = idx >> 5, r = idx & 31;
        float v = __uint_as_float(coefT[j * 33 + r]);
        unsigned short hi = f2bf(v);
        unsigned short lo = f2bf(v - bf2f(hi));
        coefT[j * 33 + r] = ((unsigned)hi << 16) | (unsigned)lo;
    }
    __syncthreads();

    int g = lane >> 4;
    int cr = lane & 15;
    f32x4 acc[5][2];
    #pragma unroll
    for (int a = 0; a < 5; ++a)
        #pragma unroll
        for (int m = 0; m < 2; ++m) acc[a][m] = (f32x4){0.f, 0.f, 0.f, 0.f};

    for (int ks = 0; ks < 16; ++ks) {
        int k0 = ks * 32;
        bf16x8 ahi[2], alo[2];
        #pragma unroll
        for (int m = 0; m < 2; ++m) {
            #pragma unroll
            for (int j = 0; j < 8; ++j) {
                unsigned v = coefT[(k0 + 8 * g + j) * 33 + m * 16 + cr];
                ahi[m][j] = (short)(v >> 16);
                alo[m][j] = (short)(v & 0xffffu);
            }
        }
        #pragma unroll
        for (int ntl = 0; ntl < 5; ++ntl) {
            int c = (wv + 4 * ntl) * 16 + cr;
            size_t off = ((size_t)(n * CPAD + c)) * Ee + k0 + 8 * g;
            bf16x8 bhi = *(const bf16x8*)(hmT_hi + off);
            bf16x8 blo = *(const bf16x8*)(hmT_lo + off);
            #pragma unroll
            for (int m = 0; m < 2; ++m) {
                acc[ntl][m] = __builtin_amdgcn_mfma_f32_16x16x32_bf16(ahi[m], bhi, acc[ntl][m], 0, 0, 0);
                acc[ntl][m] = __builtin_amdgcn_mfma_f32_16x16x32_bf16(ahi[m], blo, acc[ntl][m], 0, 0, 0);
                acc[ntl][m] = __builtin_amdgcn_mfma_f32_16x16x32_bf16(alo[m], bhi, acc[ntl][m], 0, 0, 0);
            }
        }
    }

    #pragma unroll
    for (int ntl = 0; ntl < 5; ++ntl) {
        int c = (wv + 4 * ntl) * 16 + cr;
        if (c < DOUT) {
            #pragma unroll
            for (int m = 0; m < 2; ++m) {
                #pragma unroll
                for (int q = 0; q < 4; ++q) {
                    int erow = row0 + m * 16 + 4 * g + q;
                    out[((size_t)n * Ee + erow) * DOUT + c] = acc[ntl][m][q];
                }
            }
        }
    }
}

// ---------------------------------------------------------------------------
extern "C" void kernel_launch(void* const* d_in, const int* in_sizes, int n_in,
                              void* d_out, int out_size, void* d_ws, size_t ws_size,
                              hipStream_t stream) {
    const float* input_state = (const float*)d_in[0];
    const int*   adj         = (const int*)  d_in[1];
    const float* node_mask   = (const float*)d_in[2];
    const float* query_vec   = (const float*)d_in[3];
    const float* W_type      = (const float*)d_in[4];
    const float* a_type      = (const float*)d_in[5];
    const float* qattn_W1    = (const float*)d_in[6];
    const float* qattn_W2    = (const float*)d_in[7];
    float* out = (float*)d_out;

    // workspace layout (same footprint as round 4-6; split path verified used)
    float* ws   = (float*)d_ws;
    float* g    = ws;                 // 76800 f (fallback path only)
    float* t1   = g    + 76800;       // 76800 f
    float* ssrc = t1   + 76800;       // 65536 f
    float* sdst = ssrc + 65536;       // 65536 f
    unsigned short* W3T_hi = (unsigned short*)(sdst + 65536);   // 102400 u16
    unsigned short* W3T_lo = W3T_hi + 320 * 320;                // 102400 u16
    unsigned short* GTh    = W3T_lo + 320 * 320;                // 81920 u16
    unsigned short* GTl    = GTh + 4 * 64 * 320;                // 81920 u16
    unsigned short* UTh    = GTl + 4 * 64 * 320;                // 163840 u16
    unsigned short* UTl    = UTh + 32 * 16 * 320;               // 163840 u16
    unsigned short* hmT_hi = UTl + 32 * 16 * 320;               // 5242880 u16
    unsigned short* hmT_lo = hmT_hi + (size_t)Nn * CPAD * Ee;   // 5242880 u16
    unsigned short* AH     = hmT_lo + (size_t)Nn * CPAD * Ee;   // 8388608 u16
    unsigned short* AL     = AH + (size_t)512 * 2048 * 8;       // 8388608 u16
    // gates partial buffers alias AH region (dead until score_kernel)
    float* t1p = (float*)AH;          // 307200 f
    float* gp  = t1p + 307200;        // 307200 f

    size_t need_split = (size_t)((char*)(AL + (size_t)512 * 2048 * 8) - (char*)d_ws);
    bool use_split = ws_size >= need_split;

    hipLaunchKernelGGL(prep_kernel, dim3(640), dim3(256), 0, stream,
                       W_type + 3 * DIN * DOUT, W3T_hi, W3T_lo, UTh, UTl, GTh, GTl);
    if (use_split) {
        hipLaunchKernelGGL(gates1_part_kernel, dim3(75, NT, 4), dim3(256), 0, stream,
                           query_vec, qattn_W1, t1p);
        hipLaunchKernelGGL(gates1_fin_kernel, dim3(75, NT), dim3(256), 0, stream,
                           t1p, t1);
        hipLaunchKernelGGL(gates2_part_kernel, dim3(75, NT, 4), dim3(256), 0, stream,
                           t1, qattn_W2, gp);
        hipLaunchKernelGGL(gates2_fin_kernel, dim3(75, NT), dim3(256), 0, stream,
                           gp, a_type, GTh, GTl);
        hipLaunchKernelGGL(uvec_mfma_kernel, dim3(5, NT), dim3(256), 0, stream,
                           W_type, GTh, GTl, UTh, UTl);
        hipLaunchKernelGGL(hm_mfma_kernel, dim3((Nn * Ee) / 32), dim3(256), 0, stream,
                           input_state, node_mask, W3T_hi, W3T_lo, UTh, UTl,
                           hmT_hi, hmT_lo, ssrc, sdst);
        hipLaunchKernelGGL(score_kernel, dim3(512), dim3(256), 0, stream,
                           adj, ssrc, sdst, AH, AL);
        hipLaunchKernelGGL(pv_kernel, dim3(512), dim3(256), 0, stream,
                           AH, AL, hmT_hi, hmT_lo, out);
    } else {
        hipLaunchKernelGGL(gates1_kernel, dim3(75, NT), dim3(256), 0, stream,
                           query_vec, qattn_W1, t1);
        hipLaunchKernelGGL(gates2_kernel, dim3(75, NT), dim3(256), 0, stream,
                           t1, qattn_W2, g);
        hipLaunchKernelGGL(uvec_kernel, dim3(NT, Nn, 8), dim3(64), 0, stream,
                           W_type, a_type, g, UTh, UTl);
        hipLaunchKernelGGL(hm_mfma_kernel, dim3((Nn * Ee) / 32), dim3(256), 0, stream,
                           input_state, node_mask, W3T_hi, W3T_lo, UTh, UTl,
                           hmT_hi, hmT_lo, ssrc, sdst);
        hipLaunchKernelGGL(attn_kernel, dim3(512), dim3(256), 0, stream,
                           adj, ssrc, sdst, hmT_hi, hmT_lo, out);
    }
}